// Round 8
// baseline (366.073 us; speedup 1.0000x reference)
//
#include <hip/hip_runtime.h>
#include <math.h>

#define BDIM 2
#define SDIM 2048
#define HIDD 2048
#define NHH 16
#define HDD 128
#define QKDD 64
#define MTOT (BDIM*SDIM)   // 4096

constexpr float LAMBDA_INIT_F = 0.3555090675909693f;  // 0.8 - 0.6*exp(-0.3)
constexpr float EPS_F = 1e-6f;
constexpr float SCALE_F = 0.125f;                     // 1/sqrt(64)

typedef float f32x4 __attribute__((ext_vector_type(4)));
typedef short bf16x8 __attribute__((ext_vector_type(8)));
typedef short bf16x4 __attribute__((ext_vector_type(4)));

#define MFMA16(a, b, c) __builtin_amdgcn_mfma_f32_16x16x32_bf16((a), (b), (c), 0, 0, 0)

__device__ __forceinline__ short f2bf(float f) {
    unsigned u = __float_as_uint(f);
    u += 0x7FFFu + ((u >> 16) & 1u);   // RNE
    return (short)(u >> 16);
}
__device__ __forceinline__ unsigned pk2(float a, float b) {
    return (unsigned)(unsigned short)f2bf(a) | ((unsigned)(unsigned short)f2bf(b) << 16);
}

__device__ __forceinline__ void gload_lds16(const void* g, void* l) {
    __builtin_amdgcn_global_load_lds(
        (const __attribute__((address_space(1))) void*)g,
        (__attribute__((address_space(3))) void*)l, 16, 0, 0);
}
__device__ __forceinline__ void waitv8() { asm volatile("s_waitcnt vmcnt(8)" ::: "memory"); }
__device__ __forceinline__ void waitv6() { asm volatile("s_waitcnt vmcnt(6)" ::: "memory"); }
__device__ __forceinline__ void waitv0() { asm volatile("s_waitcnt vmcnt(0)" ::: "memory"); }
__device__ __forceinline__ void waitl0() { asm volatile("s_waitcnt lgkmcnt(0)" ::: "memory"); }
#define SBAR()   __builtin_amdgcn_s_barrier()
#define SCHEDB() __builtin_amdgcn_sched_barrier(0)

// ---------------------------------------------------------------- lambda ----
__global__ void lambda_kernel(const float* __restrict__ lq1, const float* __restrict__ lk1,
                              const float* __restrict__ lq2, const float* __restrict__ lk2,
                              float* __restrict__ lam_out) {
    int l = threadIdx.x;
    float d1 = lq1[l] * lk1[l] + lq1[l + 64] * lk1[l + 64];
    float d2 = lq2[l] * lk2[l] + lq2[l + 64] * lk2[l + 64];
#pragma unroll
    for (int o = 32; o > 0; o >>= 1) {
        d1 += __shfl_down(d1, o);
        d2 += __shfl_down(d2, o);
    }
    if (l == 0) lam_out[0] = expf(d1) - expf(d2) + LAMBDA_INIT_F;
}

// ---------------------------------------------------------------- convert ---
__global__ __launch_bounds__(256) void conv_x(const float* __restrict__ s0,
                                              const float* __restrict__ s1,
                                              const float* __restrict__ s2,
                                              short* __restrict__ dst, int n) {
    const float* src = (blockIdx.y == 0) ? s0 : (blockIdx.y == 1) ? s1 : s2;
    short* out = dst + (size_t)blockIdx.y * n;
    int i = (blockIdx.x * 256 + threadIdx.x) * 8;
    if (i >= n) return;
    float4 a = *(const float4*)&src[i];
    float4 b = *(const float4*)&src[i + 4];
    uint4 o;
    o.x = pk2(a.x, a.y); o.y = pk2(a.z, a.w);
    o.z = pk2(b.x, b.y); o.w = pk2(b.z, b.w);
    *(uint4*)&out[i] = o;
}
__global__ __launch_bounds__(256) void conv_w(const float* __restrict__ s0,
                                              const float* __restrict__ s1,
                                              const float* __restrict__ s2,
                                              const float* __restrict__ s3,
                                              short* __restrict__ dst, int n) {
    const float* src = (blockIdx.y == 0) ? s0 : (blockIdx.y == 1) ? s1
                     : (blockIdx.y == 2) ? s2 : s3;
    short* out = dst + (size_t)blockIdx.y * n;
    int i = (blockIdx.x * 256 + threadIdx.x) * 8;
    if (i >= n) return;
    float4 a = *(const float4*)&src[i];
    float4 b = *(const float4*)&src[i + 4];
    uint4 o;
    o.x = pk2(a.x, a.y); o.y = pk2(a.z, a.w);
    o.z = pk2(b.x, b.y); o.w = pk2(b.z, b.w);
    *(uint4*)&out[i] = o;
}

#define GK 2048

// ===================== 256x256 8-phase QKV GEMM (m201 template) =============
// 8 waves (2M x 4N), BK=64, 2 K-tile LDS double-buffer (128 KiB).
// Quadrant order per K-tile: (0,0),(0,1),(1,0),(1,1).
// Region free/stage ledger (iteration processes t=buf0, t+1=buf1):
//   p1: stage B1(t+1)->buf1   (buf1 B-qn1 last read prev p8)
//   p2: stage A1(t+1)->buf1   (buf1 A-qm1 last read prev p8)   + vmcnt(6)
//   p3: stage A0(t+2)->buf0   (A-qm0 last read p2)
//   p4: stage B0(t+2)->buf0   (B-qn0 last read p3)              + vmcnt(6)
//   p5: stage B1(t+2)->buf0   (B-qn1 last read p4)
//   p6: stage A1(t+2)->buf0   (A-qm1 last read p4)              + vmcnt(6)
//   p7: stage A0(t+3)->buf1   (buf1 A-qm0 last read p6)
//   p8: stage B0(t+3)->buf1   (buf1 B-qn0 last read p7)         + vmcnt(6)
// Read deadlines all covered: 2 loads/phase; vmcnt(6) at even-phase end +
// end barrier retires everything >=4 phases old; every read is >=4 phases
// after (or separated by a covering wait from) its stage. Steady state: 6
// loads (3 half-tiles) in flight; never drained mid-loop.

#define STAGE_A(BUF, QM, K0) do {                                              \
    _Pragma("unroll") for (int j = 0; j < 2; ++j)                              \
        gload_lds16(X + (size_t)(bm + arow0[j] + (QM) * 64) * GK + (K0) + scol,\
                    &lds[(BUF) * 16384 + adst0[j] + (QM) * 4096]);             \
} while (0)

#define STAGE_B(BUF, QN, K0) do {                                              \
    _Pragma("unroll") for (int j = 0; j < 2; ++j)                              \
        gload_lds16(W + (size_t)(bn + brow0[j] + (QN) * 32) * GK + (K0) + scol,\
                    &lds[32768 + (BUF) * 16384 + bdst0[j] + (QN) * 2048]);     \
} while (0)

#define PHASE(BUF, QM, QN, STAGE, WAITC) do {                                  \
    bf16x8 aF[4][2]; bf16x8 bF[2][2];                                          \
    _Pragma("unroll") for (int mp = 0; mp < 4; ++mp)                           \
        _Pragma("unroll") for (int kk = 0; kk < 2; ++kk)                       \
            aF[mp][kk] = *(const bf16x8*)&lds[(BUF) * 16384 +                  \
                (wr * 128 + (QM) * 64 + mp * 16 + lq) * 64 +                   \
                ((kk * 32 + lg * 8) ^ rswl)];                                  \
    _Pragma("unroll") for (int np = 0; np < 2; ++np)                           \
        _Pragma("unroll") for (int kk = 0; kk < 2; ++kk)                       \
            bF[np][kk] = *(const bf16x8*)&lds[32768 + (BUF) * 16384 +          \
                (wc * 64 + (QN) * 32 + np * 16 + lq) * 64 +                    \
                ((kk * 32 + lg * 8) ^ rswl)];                                  \
    STAGE;                                                                     \
    SBAR();                                                                    \
    waitl0(); SCHEDB();                                                        \
    __builtin_amdgcn_s_setprio(1);                                             \
    _Pragma("unroll") for (int kk = 0; kk < 2; ++kk)                           \
        _Pragma("unroll") for (int mp = 0; mp < 4; ++mp)                       \
            _Pragma("unroll") for (int np = 0; np < 2; ++np)                   \
                acc[(QM) * 4 + mp][(QN) * 2 + np] =                            \
                    MFMA16(aF[mp][kk], bF[np][kk],                             \
                           acc[(QM) * 4 + mp][(QN) * 2 + np]);                 \
    __builtin_amdgcn_s_setprio(0);                                             \
    WAITC;                                                                     \
    SBAR();                                                                    \
} while (0)

__global__ __launch_bounds__(512, 1) void qkv_gemm256(
        const short* __restrict__ Xq, const short* __restrict__ Xk, const short* __restrict__ Xv,
        const short* __restrict__ Wb, short* __restrict__ Qb, short* __restrict__ Kb,
        short* __restrict__ Vb, const float* __restrict__ cosE, const float* __restrict__ sinE) {
    __shared__ short lds[65536];   // A: [0,32768) 2 bufs; B: [32768,65536)

    const int tid = threadIdx.x;
    const int w = tid >> 6, l = tid & 63;
    const int lq = l & 15, lg = l >> 4;
    const int wr = w >> 2, wc = w & 3;           // 2 x 4 wave grid
    const int rswl = (lq & 7) << 3;

    // XCD-aware bijective swizzle (384 % 8 == 0)
    const int bid = blockIdx.x;
    const int swz = (bid & 7) * 48 + (bid >> 3);
    const int z   = swz >> 7;                     // 3 tensors x 128 blocks
    const int rr  = swz & 127;
    const int by  = rr >> 3;                      // 16 M-blocks
    const int bx  = rr & 7;                       // 8 N-blocks
    const int bm = by * 256, bn = bx * 256;

    const short* X = (z == 0) ? Xq : (z == 1) ? Xk : Xv;
    const short* W = Wb + (size_t)z * HIDD * HIDD;
    short* Cb      = (z == 0) ? Qb : (z == 1) ? Kb : Vb;

    // staging geometry: chunk c = w*2+j covers 8 rows; lane l -> row +l>>3,
    // 16B group l&7; global col pre-swizzled so LDS dest is linear.
    int arow0[2], brow0[2], adst0[2], bdst0[2];
#pragma unroll
    for (int j = 0; j < 2; ++j) {
        const int c  = w * 2 + j;
        const int aRS = (c >> 3) * 128 + (c & 7) * 8;   // + QM*64
        const int bRS = (c >> 2) * 64 + (c & 3) * 8;    // + QN*32
        arow0[j] = aRS + (l >> 3);
        brow0[j] = bRS + (l >> 3);
        adst0[j] = aRS * 64;
        bdst0[j] = bRS * 64;
    }
    const int scol = ((l & 7) ^ (l >> 3)) * 8;

    f32x4 acc[8][4] = {};

    // ---- prologue: A0(0),B0(0),B1(0),A1(0),A0(1),B0(1) -> enter steady ----
    STAGE_A(0, 0, 0); STAGE_B(0, 0, 0);
    STAGE_B(0, 1, 0); STAGE_A(0, 1, 0);
    STAGE_A(1, 0, 64); STAGE_B(1, 0, 64);
    waitv6(); SBAR();

    for (int it = 0; it < 15; ++it) {
        const int t  = 2 * it;
        const int k1 = (t + 1) * 64, k2 = (t + 2) * 64, k3 = (t + 3) * 64;
        PHASE(0, 0, 0, STAGE_B(1, 1, k1), (void)0);
        PHASE(0, 0, 1, STAGE_A(1, 1, k1), waitv6());
        PHASE(0, 1, 0, STAGE_A(0, 0, k2), (void)0);
        PHASE(0, 1, 1, STAGE_B(0, 0, k2), waitv6());
        PHASE(1, 0, 0, STAGE_B(0, 1, k2), (void)0);
        PHASE(1, 0, 1, STAGE_A(0, 1, k2), waitv6());
        PHASE(1, 1, 0, STAGE_A(1, 0, k3), (void)0);
        PHASE(1, 1, 1, STAGE_B(1, 0, k3), waitv6());
    }
    // ---- last iteration t=30: finish staging tile 31, then drain ----
    PHASE(0, 0, 0, STAGE_B(1, 1, 31 * 64), (void)0);
    PHASE(0, 0, 1, STAGE_A(1, 1, 31 * 64), waitv6());
    PHASE(0, 1, 0, (void)0, (void)0);
    PHASE(0, 1, 1, (void)0, waitv0());
    PHASE(1, 0, 0, (void)0, (void)0);
    PHASE(1, 0, 1, (void)0, (void)0);
    PHASE(1, 1, 0, (void)0, (void)0);
    PHASE(1, 1, 1, (void)0, (void)0);

    // ---- epilogue: RoPE (z<2) + bf16 store ----
    const bool dorope = (z < 2);
#pragma unroll
    for (int m = 0; m < 8; ++m)
#pragma unroll
        for (int n = 0; n < 4; ++n) {
            const int row0 = bm + wr * 128 + m * 16 + lg * 4;
            const int col  = bn + wc * 64 + n * 16 + lq;
#pragma unroll
            for (int r = 0; r < 4; ++r) {
                float vv = acc[m][n][r];
                if (dorope) {
                    const int s  = (row0 + r) & (SDIM - 1);
                    const int c6 = col & 63;
                    const float cv = cosE[s * HDD + c6];
                    const float sv = sinE[s * HDD + c6];
                    const float p = __shfl_xor(vv, 1);
                    vv = (col & 1) ? vv * cv + p * sv : vv * cv - p * sv;
                }
                Cb[(size_t)(row0 + r) * HIDD + col] = f2bf(vv);
            }
        }
}

// ============== 128x128 2-deep pipeline (round-7, kept for o_gemm) ==========
__device__ __forceinline__ void gemm_mainloop(
        const short* __restrict__ X, const short* __restrict__ W,
        short* As, short* Bs, f32x4 acc[4][4],
        int bm, int bn, int w, int l, int lq, int lg, int wr, int wc) {
    const int scol = (((l & 7) ^ (l >> 3)) << 3);
    const int rsw  = (lq & 7) << 3;
    const short* aS[4]; const short* bS[4];
#pragma unroll
    for (int i = 0; i < 4; ++i) {
        const int c = w * 4 + i;
        aS[i] = X + (size_t)(bm + c * 8 + (l >> 3)) * GK + scol;
        bS[i] = W + (size_t)(bn + c * 8 + (l >> 3)) * GK + scol;
    }
    const int dOff = (w * 4) * 512;

#pragma unroll
    for (int i = 0; i < 4; ++i) {
        gload_lds16(aS[i], As + dOff + i * 512);
        gload_lds16(bS[i], Bs + dOff + i * 512);
    }
#pragma unroll
    for (int i = 0; i < 4; ++i) {
        gload_lds16(aS[i] + 64, As + 8192 + dOff + i * 512);
        gload_lds16(bS[i] + 64, Bs + 8192 + dOff + i * 512);
    }
    waitv8();
    SBAR();

    for (int t = 0; t < 30; ++t) {
        const short* Ab = As + (t & 1) * 8192;
        const short* Bb = Bs + (t & 1) * 8192;
        bf16x8 a[4][2], b[4][2];
#pragma unroll
        for (int m = 0; m < 4; ++m)
#pragma unroll
            for (int kk = 0; kk < 2; ++kk)
                a[m][kk] = *(const bf16x8*)&Ab[(wr * 64 + m * 16 + lq) * 64 + ((kk * 32 + lg * 8) ^ rsw)];
#pragma unroll
        for (int n = 0; n < 4; ++n)
#pragma unroll
            for (int kk = 0; kk < 2; ++kk)
                b[n][kk] = *(const bf16x8*)&Bb[(wc * 64 + n * 16 + lq) * 64 + ((kk * 32 + lg * 8) ^ rsw)];
        waitl0(); SCHEDB();
        SBAR();
        {
            short* Ad = As + (t & 1) * 8192 + dOff;
            short* Bd = Bs + (t & 1) * 8192 + dOff;
#pragma unroll
            for (int i = 0; i < 4; ++i) {
                gload_lds16(aS[i] + (t + 2) * 64, Ad + i * 512);
                gload_lds16(bS[i] + (t + 2) * 64, Bd + i * 512);
            }
        }
        SCHEDB();
#pragma unroll
        for (int kk = 0; kk < 2; ++kk)
#pragma unroll
            for (int m = 0; m < 4; ++m)
#pragma unroll
                for (int n = 0; n < 4; ++n)
                    acc[m][n] = MFMA16(a[m][kk], b[n][kk], acc[m][n]);
        waitv8();
        SBAR();
    }
    {
        bf16x8 a[4][2], b[4][2];
#pragma unroll
        for (int m = 0; m < 4; ++m)
#pragma unroll
            for (int kk = 0; kk < 2; ++kk)
                a[m][kk] = *(const bf16x8*)&As[(wr * 64 + m * 16 + lq) * 64 + ((kk * 32 + lg * 8) ^ rsw)];
#pragma unroll
        for (int n = 0; n < 4; ++n)
#pragma unroll
            for (int kk = 0; kk < 2; ++kk)
                b[n][kk] = *(const bf16x8*)&Bs[(wc * 64 + n * 16 + lq) * 64 + ((kk * 32 + lg * 8) ^ rsw)];
        waitl0(); SCHEDB();
        SBAR();
#pragma unroll
        for (int kk = 0; kk < 2; ++kk)
#pragma unroll
            for (int m = 0; m < 4; ++m)
#pragma unroll
                for (int n = 0; n < 4; ++n)
                    acc[m][n] = MFMA16(a[m][kk], b[n][kk], acc[m][n]);
        waitv0();
        SBAR();
    }
    {
        bf16x8 a[4][2], b[4][2];
#pragma unroll
        for (int m = 0; m < 4; ++m)
#pragma unroll
            for (int kk = 0; kk < 2; ++kk)
                a[m][kk] = *(const bf16x8*)&As[8192 + (wr * 64 + m * 16 + lq) * 64 + ((kk * 32 + lg * 8) ^ rsw)];
#pragma unroll
        for (int n = 0; n < 4; ++n)
#pragma unroll
            for (int kk = 0; kk < 2; ++kk)
                b[n][kk] = *(const bf16x8*)&Bs[8192 + (wc * 64 + n * 16 + lq) * 64 + ((kk * 32 + lg * 8) ^ rsw)];
#pragma unroll
        for (int kk = 0; kk < 2; ++kk)
#pragma unroll
            for (int m = 0; m < 4; ++m)
#pragma unroll
                for (int n = 0; n < 4; ++n)
                    acc[m][n] = MFMA16(a[m][kk], b[n][kk], acc[m][n]);
    }
}

__global__ __launch_bounds__(256) void o_gemm(const short* __restrict__ Ab,
                                              const short* __restrict__ Bb,
                                              float* __restrict__ C) {
    __shared__ short As[2 * 128 * 64];
    __shared__ short Bs[2 * 128 * 64];
    const int tid = threadIdx.x;
    const int w = tid >> 6, l = tid & 63;
    const int lq = l & 15, lg = l >> 4;
    const int wr = w >> 1, wc = w & 1;
    const int bm = blockIdx.y * 128;
    const int bn = blockIdx.x * 128;

    f32x4 acc[4][4] = {};
    gemm_mainloop(Ab, Bb, As, Bs, acc, bm, bn, w, l, lq, lg, wr, wc);

#pragma unroll
    for (int m = 0; m < 4; ++m)
#pragma unroll
        for (int n = 0; n < 4; ++n) {
            const int row0 = bm + wr * 64 + m * 16 + lg * 4;
            const int col  = bn + wc * 64 + n * 16 + lq;
#pragma unroll
            for (int r = 0; r < 4; ++r)
                C[(size_t)(row0 + r) * HIDD + col] = acc[m][n][r];
        }
}

// ------------------------------------------------- MFMA differential flash --
// (round-7 validated, unchanged)
#define KVB 64

__device__ __forceinline__ bf16x8 pack_pa(const float p0[4], const float p1[4]) {
    union { unsigned u[4]; bf16x8 v; } r;
    r.u[0] = pk2(p0[0], p0[1]);
    r.u[1] = pk2(p0[2], p0[3]);
    r.u[2] = pk2(p1[0], p1[1]);
    r.u[3] = pk2(p1[2], p1[3]);
    return r.v;
}

__device__ __forceinline__ void softmax_step(
        f32x4 sc[4], float& M, float& L, f32x4 O[8], bf16x8 pa[2],
        int t0, int qg, int lg, bool domask) {
#pragma unroll
    for (int sub = 0; sub < 4; ++sub)
#pragma unroll
        for (int r = 0; r < 4; ++r) {
            float s = sc[sub][r] * SCALE_F;
            if (domask) {
                int key = t0 + sub * 16 + lg * 4 + r;
                s = (key <= qg) ? s : -1e30f;
            }
            sc[sub][r] = s;
        }
    float mx = -1e30f;
#pragma unroll
    for (int sub = 0; sub < 4; ++sub) {
        float a01 = fmaxf(sc[sub][0], sc[sub][1]);
        float a23 = fmaxf(sc[sub][2], sc[sub][3]);
        mx = fmaxf(mx, fmaxf(a01, a23));
    }
    mx = fmaxf(mx, __shfl_xor(mx, 16));
    mx = fmaxf(mx, __shfl_xor(mx, 32));
    if (__ballot(mx > M + 8.f)) {
        const float Mn = fmaxf(M, mx);
        const float a = __expf(M - Mn);
        M = Mn;
        L *= a;
        float ar[4];
#pragma unroll
        for (int r = 0; r < 4; ++r) ar[r] = __shfl(a, lg * 4 + r);
#pragma unroll
        for (int d = 0; d < 8; ++d) {
            O[d][0] *= ar[0]; O[d][1] *= ar[1]; O[d][2] *= ar[2]; O[d][3] *= ar[3];
        }
    }
    float p[4][4];
    float ps = 0.f;
#pragma unroll
    for (int sub = 0; sub < 4; ++sub) {
#pragma unroll
        for (int r = 0; r < 4; ++r) p[sub][r] = __expf(sc[sub][r] - M);
        ps += (p[sub][0] + p[sub][1]) + (p[sub][2] + p[sub][3]);
    }
    ps += __shfl_xor(ps, 16);
    ps += __shfl_xor(ps, 32);
    L += ps;
    pa[0] = pack_pa(p[0], p[1]);
    pa[1] = pack_pa(p[2], p[3]);
}

__global__ __launch_bounds__(256, 2) void flash_mfma(
        const short* __restrict__ Qb, const short* __restrict__ Kb,
        const short* __restrict__ Vb, const float* __restrict__ gnw,
        const float* __restrict__ lam_p, short* __restrict__ Hob) {
    __shared__ short Ksh[KVB * 128];
    __shared__ short VT[HDD * 72];

    const int tid = threadIdx.x;
    const int w  = tid >> 6;
    const int l  = tid & 63;
    const int lq = l & 15;
    const int lg = l >> 4;

    const int blk = blockIdx.x;
    const int bh  = blk & 31;
    const int bx  = 31 - (blk >> 5);
    const int b = bh >> 4, h = bh & 15;
    const int s0 = bx * 64;
    const float lam = lam_p[0];

    const int qg = s0 + w * 16 + lq;
    const short* qrow = Qb + ((size_t)(b * SDIM + qg)) * HIDD + h * HDD;
    bf16x8 qf[2][2];
#pragma unroll
    for (int br = 0; br < 2; ++br)
#pragma unroll
        for (int ks = 0; ks < 2; ++ks)
            qf[br][ks] = *(const bf16x8*)(qrow + br * 64 + ks * 32 + lg * 8);

    int kkey[4], kcol[4];
#pragma unroll
    for (int i = 0; i < 4; ++i) {
        kkey[i] = w * 16 + i * 4 + lg;
        kcol[i] = (lq * 8) ^ ((kkey[i] & 7) << 3);
    }
    const int kp = tid & 31, dq = tid >> 5;

    const short* Kbase = Kb + ((size_t)(b * SDIM)) * HIDD + h * HDD;
    const short* Vbase = Vb + ((size_t)(b * SDIM)) * HIDD + h * HDD;

    float M1 = -1e30f, M2 = -1e30f, L1 = 0.f, L2 = 0.f;
    f32x4 O1[8] = {}; f32x4 O2[8] = {};

    const int ntmax = bx + 1;
    const int qmin = s0 + w * 16;
    const int ntw = (qmin >> 6) + 1;

    for (int t = 0; t < ntmax; ++t) {
        const size_t trow = (size_t)t * KVB * HIDD;
        __syncthreads();
#pragma unroll
        for (int i = 0; i < 4; ++i)
            gload_lds16(Kbase + trow + (size_t)kkey[i] * HIDD + kcol[i],
                        &Ksh[w * 2048 + i * 512]);
        {
            const short* v0 = Vbase + trow + (size_t)(2 * kp) * HIDD + dq * 16;
            const short* v1 = v0 + HIDD;
            bf16x8 v00 = *(const bf16x8*)v0;
            bf16x8 v01 = *(const bf16x8*)(v0 + 8);
            bf16x8 v10 = *(const bf16x8*)v1;
            bf16x8 v11 = *(const bf16x8*)(v1 + 8);
#pragma unroll
            for (int j = 0; j < 8; ++j) {
                unsigned ua = (unsigned)(unsigned short)v00[j] |
                              ((unsigned)(unsigned short)v10[j] << 16);
                *(unsigned*)&VT[(dq * 16 + j) * 72 + 2 * kp] = ua;
                unsigned ub = (unsigned)(unsigned short)v01[j] |
                              ((unsigned)(unsigned short)v11[j] << 16);
                *(unsigned*)&VT[(dq * 16 + 8 + j) * 72 + 2 * kp] = ub;
            }
        }
        __syncthreads();
        if (t >= ntw) continue;

        f32x4 sc1[4] = {}; f32x4 sc2[4] = {};
        const int rsw = (lq & 7) << 3;
        __builtin_amdgcn_s_setprio(1);
#pragma unroll
        for (int sub = 0; sub < 4; ++sub) {
            const int rbase = (sub * 16 + lq) * 128;
            bf16x8 k00 = *(const bf16x8*)&Ksh[rbase + ((lg * 8) ^ rsw)];
            bf16x8 k01 = *(const bf16x8*)&Ksh[rbase + ((32 + lg * 8) ^ rsw)];
            bf16x8 k10 = *(const bf16x8*)&Ksh[rbase + ((64 + lg * 8) ^ rsw)];
            bf16x8 k11 = *(const bf16x8*)&Ksh[rbase + ((96 + lg * 8) ^ rsw)];
            sc1[sub] = MFMA16(k00, qf[0][0], sc1[sub]);
            sc1[sub] = MFMA16(k01, qf[0][1], sc1[sub]);
            sc2[sub] = MFMA16(k10, qf[1][0], sc2[sub]);
            sc2[sub] = MFMA16(k11, qf[1][1], sc2[sub]);
        }
        __builtin_amdgcn_s_setprio(0);
        const int t0 = t * KVB;
        const bool domask = (t0 + KVB - 1 > qmin);
        bf16x8 pa1[2], pa2[2];
        softmax_step(sc1, M1, L1, O1, pa1, t0, qg, lg, domask);
        softmax_step(sc2, M2, L2, O2, pa2, t0, qg, lg, domask);

        __builtin_amdgcn_s_setprio(1);
#pragma unroll
        for (int d0 = 0; d0 < 8; ++d0) {
            const short* vrow = &VT[(d0 * 16 + lq) * 72];
            bf16x4 a0 = *(const bf16x4*)&vrow[lg * 4];
            bf16x4 a1 = *(const bf16x4*)&vrow[16 + lg * 4];
            bf16x4 b0 = *(const bf16x4*)&vrow[32 + lg * 4];
            bf16x4 b1 = *(const bf16x4*)&vrow[48 + lg * 4];
            bf16x8 vb0 = __builtin_shufflevector(a0, a1, 0, 1, 2, 3, 4, 5, 6, 7);
            bf16x8 vb1 = __builtin_shufflevector(b0, b1, 0, 1, 2, 3, 4, 5, 6, 7);
            O1[d0] = MFMA16(pa1[0], vb0, O1[d0]);
            O1[d0] = MFMA16(pa1[1], vb1, O1[d0]);
            O2[d0] = MFMA16(pa2[0], vb0, O2[d0]);
            O2[d0] = MFMA16(pa2[1], vb1, O2[d0]);
        }
        __builtin_amdgcn_s_setprio(0);
    }

    const float inv1 = 1.f / L1;
    const float inv2 = lam / L2;
    float i1[4], i2[4];
#pragma unroll
    for (int r = 0; r < 4; ++r) {
        i1[r] = __shfl(inv1, lg * 4 + r);
        i2[r] = __shfl(inv2, lg * 4 + r);
    }
    float gn[8];
#pragma unroll
    for (int d = 0; d < 8; ++d) gn[d] = gnw[d * 16 + lq];
    float od[8][4];
    float ss[4] = {0.f, 0.f, 0.f, 0.f};
#pragma unroll
    for (int d = 0; d < 8; ++d)
#pragma unroll
        for (int r = 0; r < 4; ++r) {
            float o = O1[d][r] * i1[r] - O2[d][r] * i2[r];
            od[d][r] = o;
            ss[r] += o * o;
        }
#pragma unroll
    for (int r = 0; r < 4; ++r) {
        ss[r] += __shfl_xor(ss[r], 1);
        ss[r] += __shfl_xor(ss[r], 2);
        ss[r] += __shfl_xor(ss[r], 4);
        ss[r] += __shfl_xor(ss[r], 8);
    }
#pragma unroll
    for (int r = 0; r < 4; ++r) {
        const float scal = rsqrtf(ss[r] * (1.0f / HDD) + EPS_F) * (1.0f - LAMBDA_INIT_F);
        const size_t orow = ((size_t)(b * SDIM + s0 + w * 16 + lg * 4 + r)) * HIDD + h * HDD;
#pragma unroll
        for (int d = 0; d < 8; ++d)
            Hob[orow + d * 16 + lq] = f2bf(od[d][r] * scal * gn[d]);
    }
}

// ----------------------------------------------------------------- launch ---
extern "C" void kernel_launch(void* const* d_in, const int* in_sizes, int n_in,
                              void* d_out, int out_size, void* d_ws, size_t ws_size,
                              hipStream_t stream) {
    const float* q   = (const float*)d_in[0];
    const float* k   = (const float*)d_in[1];
    const float* v   = (const float*)d_in[2];
    const float* Wq  = (const float*)d_in[3];
    const float* Wk  = (const float*)d_in[4];
    const float* Wv  = (const float*)d_in[5];
    const float* Wo  = (const float*)d_in[6];
    const float* lq1 = (const float*)d_in[7];
    const float* lk1 = (const float*)d_in[8];
    const float* lq2 = (const float*)d_in[9];
    const float* lk2 = (const float*)d_in[10];
    const float* gnw = (const float*)d_in[11];
    const float* cosE = (const float*)d_in[12];
    const float* sinE = (const float*)d_in[13];
    float* out = (float*)d_out;

    const size_t TEN = (size_t)BDIM * SDIM * HIDD;  // 8388608
    const int   WN  = HIDD * HIDD;                  // 4194304

    short* wsS = (short*)d_ws;
    short* Qb   = wsS;
    short* Kb   = wsS + TEN;
    short* Vb   = wsS + 2 * TEN;
    short* xqkv = wsS + 3 * TEN;
    short* wb4  = wsS + 6 * TEN;
    float* lamp = (float*)(wsS + 6 * TEN + (size_t)4 * WN);
    short* Hob  = xqkv;

    lambda_kernel<<<1, 64, 0, stream>>>(lq1, lk1, lq2, lk2, lamp);

    dim3 gx((int)(TEN / 8 / 256), 3);
    conv_x<<<gx, 256, 0, stream>>>(q, k, v, xqkv, (int)TEN);
    dim3 gw(WN / 8 / 256, 4);
    conv_w<<<gw, 256, 0, stream>>>(Wq, Wk, Wv, Wo, wb4, WN);

    qkv_gemm256<<<384, 512, 0, stream>>>(xqkv, xqkv + TEN, xqkv + 2 * TEN, wb4,
                                         Qb, Kb, Vb, cosE, sinE);

    flash_mfma<<<(SDIM / 64) * BDIM * NHH, 256, 0, stream>>>(Qb, Kb, Vb, gnw, lamp, Hob);

    dim3 go(HIDD / 128, MTOT / 128);
    o_gemm<<<go, 256, 0, stream>>>(Hob, wb4 + (size_t)3 * WN, out);
}

// Round 9
// 322.381 us; speedup vs baseline: 1.1355x; 1.1355x over previous
//
#include <hip/hip_runtime.h>
#include <math.h>

#define BDIM 2
#define SDIM 2048
#define HIDD 2048
#define NHH 16
#define HDD 128
#define QKDD 64
#define MTOT (BDIM*SDIM)   // 4096

constexpr float LAMBDA_INIT_F = 0.3555090675909693f;  // 0.8 - 0.6*exp(-0.3)
constexpr float EPS_F = 1e-6f;
constexpr float SCALE_F = 0.125f;                     // 1/sqrt(64)

typedef float f32x4 __attribute__((ext_vector_type(4)));
typedef short bf16x8 __attribute__((ext_vector_type(8)));
typedef short bf16x4 __attribute__((ext_vector_type(4)));

#define MFMA16(a, b, c) __builtin_amdgcn_mfma_f32_16x16x32_bf16((a), (b), (c), 0, 0, 0)

__device__ __forceinline__ short f2bf(float f) {
    unsigned u = __float_as_uint(f);
    u += 0x7FFFu + ((u >> 16) & 1u);   // RNE
    return (short)(u >> 16);
}
__device__ __forceinline__ unsigned pk2(float a, float b) {
    return (unsigned)(unsigned short)f2bf(a) | ((unsigned)(unsigned short)f2bf(b) << 16);
}

__device__ __forceinline__ void gload_lds16(const void* g, void* l) {
    __builtin_amdgcn_global_load_lds(
        (const __attribute__((address_space(1))) void*)g,
        (__attribute__((address_space(3))) void*)l, 16, 0, 0);
}
__device__ __forceinline__ void waitv8() { asm volatile("s_waitcnt vmcnt(8)" ::: "memory"); }
__device__ __forceinline__ void waitv0() { asm volatile("s_waitcnt vmcnt(0)" ::: "memory"); }
__device__ __forceinline__ void waitl0() { asm volatile("s_waitcnt lgkmcnt(0)" ::: "memory"); }
#define SBAR()   __builtin_amdgcn_s_barrier()
#define SCHEDB() __builtin_amdgcn_sched_barrier(0)

// ---------------------------------------------------------------- lambda ----
__global__ void lambda_kernel(const float* __restrict__ lq1, const float* __restrict__ lk1,
                              const float* __restrict__ lq2, const float* __restrict__ lk2,
                              float* __restrict__ lam_out) {
    int l = threadIdx.x;
    float d1 = lq1[l] * lk1[l] + lq1[l + 64] * lk1[l + 64];
    float d2 = lq2[l] * lk2[l] + lq2[l + 64] * lk2[l + 64];
#pragma unroll
    for (int o = 32; o > 0; o >>= 1) {
        d1 += __shfl_down(d1, o);
        d2 += __shfl_down(d2, o);
    }
    if (l == 0) lam_out[0] = expf(d1) - expf(d2) + LAMBDA_INIT_F;
}

// ---------------------------------------------------------------- convert ---
__global__ __launch_bounds__(256) void conv_x(const float* __restrict__ s0,
                                              const float* __restrict__ s1,
                                              const float* __restrict__ s2,
                                              short* __restrict__ dst, int n) {
    const float* src = (blockIdx.y == 0) ? s0 : (blockIdx.y == 1) ? s1 : s2;
    short* out = dst + (size_t)blockIdx.y * n;
    int i = (blockIdx.x * 256 + threadIdx.x) * 8;
    if (i >= n) return;
    float4 a = *(const float4*)&src[i];
    float4 b = *(const float4*)&src[i + 4];
    uint4 o;
    o.x = pk2(a.x, a.y); o.y = pk2(a.z, a.w);
    o.z = pk2(b.x, b.y); o.w = pk2(b.z, b.w);
    *(uint4*)&out[i] = o;
}
__global__ __launch_bounds__(256) void conv_w(const float* __restrict__ s0,
                                              const float* __restrict__ s1,
                                              const float* __restrict__ s2,
                                              const float* __restrict__ s3,
                                              short* __restrict__ dst, int n) {
    const float* src = (blockIdx.y == 0) ? s0 : (blockIdx.y == 1) ? s1
                     : (blockIdx.y == 2) ? s2 : s3;
    short* out = dst + (size_t)blockIdx.y * n;
    int i = (blockIdx.x * 256 + threadIdx.x) * 8;
    if (i >= n) return;
    float4 a = *(const float4*)&src[i];
    float4 b = *(const float4*)&src[i + 4];
    uint4 o;
    o.x = pk2(a.x, a.y); o.y = pk2(a.z, a.w);
    o.z = pk2(b.x, b.y); o.w = pk2(b.z, b.w);
    *(uint4*)&out[i] = o;
}

// ------------------------------------------------------------ bf16 GEMM -----
// C[M,N] = X[M,K](bf16) @ W[N,K]^T(bf16). 128x128 tile, BK=64, 4 waves (2x2).
// Double-buffered LDS + counted vmcnt pipeline (round-7 validated).
#define GK 2048

__device__ __forceinline__ void gemm_mainloop(
        const short* __restrict__ X, const short* __restrict__ W,
        short* As, short* Bs, f32x4 acc[4][4],
        int bm, int bn, int w, int l, int lq, int lg, int wr, int wc) {
    const int scol = (((l & 7) ^ (l >> 3)) << 3);
    const int rsw  = (lq & 7) << 3;
    const short* aS[4]; const short* bS[4];
#pragma unroll
    for (int i = 0; i < 4; ++i) {
        const int c = w * 4 + i;
        aS[i] = X + (size_t)(bm + c * 8 + (l >> 3)) * GK + scol;
        bS[i] = W + (size_t)(bn + c * 8 + (l >> 3)) * GK + scol;
    }
    const int dOff = (w * 4) * 512;

#pragma unroll
    for (int i = 0; i < 4; ++i) {
        gload_lds16(aS[i], As + dOff + i * 512);
        gload_lds16(bS[i], Bs + dOff + i * 512);
    }
#pragma unroll
    for (int i = 0; i < 4; ++i) {
        gload_lds16(aS[i] + 64, As + 8192 + dOff + i * 512);
        gload_lds16(bS[i] + 64, Bs + 8192 + dOff + i * 512);
    }
    waitv8();
    SBAR();

    for (int t = 0; t < 30; ++t) {
        const short* Ab = As + (t & 1) * 8192;
        const short* Bb = Bs + (t & 1) * 8192;
        bf16x8 a[4][2], b[4][2];
#pragma unroll
        for (int m = 0; m < 4; ++m)
#pragma unroll
            for (int kk = 0; kk < 2; ++kk)
                a[m][kk] = *(const bf16x8*)&Ab[(wr * 64 + m * 16 + lq) * 64 + ((kk * 32 + lg * 8) ^ rsw)];
#pragma unroll
        for (int n = 0; n < 4; ++n)
#pragma unroll
            for (int kk = 0; kk < 2; ++kk)
                b[n][kk] = *(const bf16x8*)&Bb[(wc * 64 + n * 16 + lq) * 64 + ((kk * 32 + lg * 8) ^ rsw)];
        waitl0(); SCHEDB();
        SBAR();
        {
            short* Ad = As + (t & 1) * 8192 + dOff;
            short* Bd = Bs + (t & 1) * 8192 + dOff;
#pragma unroll
            for (int i = 0; i < 4; ++i) {
                gload_lds16(aS[i] + (t + 2) * 64, Ad + i * 512);
                gload_lds16(bS[i] + (t + 2) * 64, Bd + i * 512);
            }
        }
        SCHEDB();
#pragma unroll
        for (int kk = 0; kk < 2; ++kk)
#pragma unroll
            for (int m = 0; m < 4; ++m)
#pragma unroll
                for (int n = 0; n < 4; ++n)
                    acc[m][n] = MFMA16(a[m][kk], b[n][kk], acc[m][n]);
        waitv8();
        SBAR();
    }
    {
        bf16x8 a[4][2], b[4][2];
#pragma unroll
        for (int m = 0; m < 4; ++m)
#pragma unroll
            for (int kk = 0; kk < 2; ++kk)
                a[m][kk] = *(const bf16x8*)&As[(wr * 64 + m * 16 + lq) * 64 + ((kk * 32 + lg * 8) ^ rsw)];
#pragma unroll
        for (int n = 0; n < 4; ++n)
#pragma unroll
            for (int kk = 0; kk < 2; ++kk)
                b[n][kk] = *(const bf16x8*)&Bs[(wc * 64 + n * 16 + lq) * 64 + ((kk * 32 + lg * 8) ^ rsw)];
        waitl0(); SCHEDB();
        SBAR();
#pragma unroll
        for (int kk = 0; kk < 2; ++kk)
#pragma unroll
            for (int m = 0; m < 4; ++m)
#pragma unroll
                for (int n = 0; n < 4; ++n)
                    acc[m][n] = MFMA16(a[m][kk], b[n][kk], acc[m][n]);
        waitv0();
        SBAR();
    }
    {
        bf16x8 a[4][2], b[4][2];
#pragma unroll
        for (int m = 0; m < 4; ++m)
#pragma unroll
            for (int kk = 0; kk < 2; ++kk)
                a[m][kk] = *(const bf16x8*)&As[8192 + (wr * 64 + m * 16 + lq) * 64 + ((kk * 32 + lg * 8) ^ rsw)];
#pragma unroll
        for (int n = 0; n < 4; ++n)
#pragma unroll
            for (int kk = 0; kk < 2; ++kk)
                b[n][kk] = *(const bf16x8*)&Bs[8192 + (wc * 64 + n * 16 + lq) * 64 + ((kk * 32 + lg * 8) ^ rsw)];
#pragma unroll
        for (int kk = 0; kk < 2; ++kk)
#pragma unroll
            for (int m = 0; m < 4; ++m)
#pragma unroll
                for (int n = 0; n < 4; ++n)
                    acc[m][n] = MFMA16(a[m][kk], b[n][kk], acc[m][n]);
    }
}

// Batched QKV projection: z=0 -> Q (RoPE), z=1 -> K (RoPE), z=2 -> V (plain).
__global__ __launch_bounds__(256) void qkv_gemm(
        const short* __restrict__ Xq, const short* __restrict__ Xk, const short* __restrict__ Xv,
        const short* __restrict__ Wb, short* __restrict__ Qb, short* __restrict__ Kb,
        short* __restrict__ Vb, const float* __restrict__ cosE, const float* __restrict__ sinE) {
    __shared__ short As[2 * 128 * 64];
    __shared__ short Bs[2 * 128 * 64];
    const int tid = threadIdx.x;
    const int w = tid >> 6, l = tid & 63;
    const int lq = l & 15, lg = l >> 4;
    const int wr = w >> 1, wc = w & 1;
    const int bm = blockIdx.y * 128;
    const int bn = blockIdx.x * 128;
    const int z  = blockIdx.z;

    const short* X = (z == 0) ? Xq : (z == 1) ? Xk : Xv;
    const short* W = Wb + (size_t)z * HIDD * HIDD;
    short* Cb      = (z == 0) ? Qb : (z == 1) ? Kb : Vb;

    f32x4 acc[4][4] = {};
    gemm_mainloop(X, W, As, Bs, acc, bm, bn, w, l, lq, lg, wr, wc);

    const bool dorope = (z < 2);
#pragma unroll
    for (int m = 0; m < 4; ++m)
#pragma unroll
        for (int n = 0; n < 4; ++n) {
            const int row0 = bm + wr * 64 + m * 16 + lg * 4;
            const int col  = bn + wc * 64 + n * 16 + lq;
#pragma unroll
            for (int r = 0; r < 4; ++r) {
                float vv = acc[m][n][r];
                if (dorope) {
                    const int s  = (row0 + r) & (SDIM - 1);
                    const int c6 = col & 63;
                    const float cv = cosE[s * HDD + c6];
                    const float sv = sinE[s * HDD + c6];
                    const float p = __shfl_xor(vv, 1);
                    vv = (col & 1) ? vv * cv + p * sv : vv * cv - p * sv;
                }
                Cb[(size_t)(row0 + r) * HIDD + col] = f2bf(vv);
            }
        }
}

// Output projection: fp32 C.
__global__ __launch_bounds__(256) void o_gemm(const short* __restrict__ Ab,
                                              const short* __restrict__ Bb,
                                              float* __restrict__ C) {
    __shared__ short As[2 * 128 * 64];
    __shared__ short Bs[2 * 128 * 64];
    const int tid = threadIdx.x;
    const int w = tid >> 6, l = tid & 63;
    const int lq = l & 15, lg = l >> 4;
    const int wr = w >> 1, wc = w & 1;
    const int bm = blockIdx.y * 128;
    const int bn = blockIdx.x * 128;

    f32x4 acc[4][4] = {};
    gemm_mainloop(Ab, Bb, As, Bs, acc, bm, bn, w, l, lq, lg, wr, wc);

#pragma unroll
    for (int m = 0; m < 4; ++m)
#pragma unroll
        for (int n = 0; n < 4; ++n) {
            const int row0 = bm + wr * 64 + m * 16 + lg * 4;
            const int col  = bn + wc * 64 + n * 16 + lq;
#pragma unroll
            for (int r = 0; r < 4; ++r)
                C[(size_t)(row0 + r) * HIDD + col] = acc[m][n][r];
        }
}

// ------------------------------------------------- MFMA differential flash --
// Round-5 math, new pipeline: double-buffered Ksh/VT; tile t+1's V reg-loads
// and K global_load_lds issued BEFORE tile t's compute; VT write after the
// compute has covered the load latency; one barrier per iteration.
#define KVB 64

__device__ __forceinline__ bf16x8 pack_pa(const float p0[4], const float p1[4]) {
    union { unsigned u[4]; bf16x8 v; } r;
    r.u[0] = pk2(p0[0], p0[1]);
    r.u[1] = pk2(p0[2], p0[3]);
    r.u[2] = pk2(p1[0], p1[1]);
    r.u[3] = pk2(p1[2], p1[3]);
    return r.v;
}

__device__ __forceinline__ void softmax_step(
        f32x4 sc[4], float& M, float& L, f32x4 O[8], bf16x8 pa[2],
        int t0, int qg, int lg, bool domask) {
#pragma unroll
    for (int sub = 0; sub < 4; ++sub)
#pragma unroll
        for (int r = 0; r < 4; ++r) {
            float s = sc[sub][r] * SCALE_F;
            if (domask) {
                int key = t0 + sub * 16 + lg * 4 + r;
                s = (key <= qg) ? s : -1e30f;
            }
            sc[sub][r] = s;
        }
    float mx = -1e30f;
#pragma unroll
    for (int sub = 0; sub < 4; ++sub) {
        float a01 = fmaxf(sc[sub][0], sc[sub][1]);
        float a23 = fmaxf(sc[sub][2], sc[sub][3]);
        mx = fmaxf(mx, fmaxf(a01, a23));
    }
    mx = fmaxf(mx, __shfl_xor(mx, 16));
    mx = fmaxf(mx, __shfl_xor(mx, 32));
    if (__ballot(mx > M + 8.f)) {           // defer-max (T13, THR=8)
        const float Mn = fmaxf(M, mx);
        const float a = __expf(M - Mn);
        M = Mn;
        L *= a;
        float ar[4];
#pragma unroll
        for (int r = 0; r < 4; ++r) ar[r] = __shfl(a, lg * 4 + r);
#pragma unroll
        for (int d = 0; d < 8; ++d) {
            O[d][0] *= ar[0]; O[d][1] *= ar[1]; O[d][2] *= ar[2]; O[d][3] *= ar[3];
        }
    }
    float p[4][4];
    float ps = 0.f;
#pragma unroll
    for (int sub = 0; sub < 4; ++sub) {
#pragma unroll
        for (int r = 0; r < 4; ++r) p[sub][r] = __expf(sc[sub][r] - M);
        ps += (p[sub][0] + p[sub][1]) + (p[sub][2] + p[sub][3]);
    }
    ps += __shfl_xor(ps, 16);
    ps += __shfl_xor(ps, 32);
    L += ps;
    pa[0] = pack_pa(p[0], p[1]);
    pa[1] = pack_pa(p[2], p[3]);
}

__global__ __launch_bounds__(256, 2) void flash_mfma(
        const short* __restrict__ Qb, const short* __restrict__ Kb,
        const short* __restrict__ Vb, const float* __restrict__ gnw,
        const float* __restrict__ lam_p, short* __restrict__ Hob) {
    __shared__ short Ksh[2][KVB * 128];   // 2 x 16 KiB, xor-swizzled 16B units
    __shared__ short VT[2][HDD * 72];     // 2 x 18 KiB, VT[d][key] stride 72

    const int tid = threadIdx.x;
    const int w  = tid >> 6;
    const int l  = tid & 63;
    const int lq = l & 15;
    const int lg = l >> 4;

    const int blk = blockIdx.x;
    const int bh  = blk & 31;
    const int bx  = 31 - (blk >> 5);      // heavy blocks first
    const int b = bh >> 4, h = bh & 15;
    const int s0 = bx * 64;
    const float lam = lam_p[0];

    const int qg = s0 + w * 16 + lq;
    const short* qrow = Qb + ((size_t)(b * SDIM + qg)) * HIDD + h * HDD;
    bf16x8 qf[2][2];
#pragma unroll
    for (int br = 0; br < 2; ++br)
#pragma unroll
        for (int ks = 0; ks < 2; ++ks)
            qf[br][ks] = *(const bf16x8*)(qrow + br * 64 + ks * 32 + lg * 8);

    int kkey[4], kcol[4];
#pragma unroll
    for (int i = 0; i < 4; ++i) {
        kkey[i] = w * 16 + i * 4 + lg;
        kcol[i] = (lq * 8) ^ ((kkey[i] & 7) << 3);
    }
    const int kp = tid & 31, dq = tid >> 5;

    const short* Kbase = Kb + ((size_t)(b * SDIM)) * HIDD + h * HDD;
    const short* Vbase = Vb + ((size_t)(b * SDIM)) * HIDD + h * HDD;

    float M1 = -1e30f, M2 = -1e30f, L1 = 0.f, L2 = 0.f;
    f32x4 O1[8] = {}; f32x4 O2[8] = {};

    const int ntmax = bx + 1;
    const int rsw = (lq & 7) << 3;

    // ---- prologue: stage tile 0 into buf 0 ----
    {
        const short* v0 = Vbase + (size_t)(2 * kp) * HIDD + dq * 16;
        bf16x8 vr0 = *(const bf16x8*)v0;
        bf16x8 vr1 = *(const bf16x8*)(v0 + 8);
        bf16x8 vr2 = *(const bf16x8*)(v0 + HIDD);
        bf16x8 vr3 = *(const bf16x8*)(v0 + HIDD + 8);
#pragma unroll
        for (int i = 0; i < 4; ++i)
            gload_lds16(Kbase + (size_t)kkey[i] * HIDD + kcol[i],
                        &Ksh[0][w * 2048 + i * 512]);
#pragma unroll
        for (int j = 0; j < 8; ++j) {
            unsigned ua = (unsigned)(unsigned short)vr0[j] |
                          ((unsigned)(unsigned short)vr2[j] << 16);
            *(unsigned*)&VT[0][(dq * 16 + j) * 72 + 2 * kp] = ua;
            unsigned ub = (unsigned)(unsigned short)vr1[j] |
                          ((unsigned)(unsigned short)vr3[j] << 16);
            *(unsigned*)&VT[0][(dq * 16 + 8 + j) * 72 + 2 * kp] = ub;
        }
        waitv0(); waitl0();
        SBAR();
    }

    for (int t = 0; t < ntmax; ++t) {
        const int c = t & 1;
        const bool stage = (t + 1 < ntmax);
        bf16x8 vr0, vr1, vr2, vr3;
        if (stage) {   // issue next tile's loads BEFORE this tile's compute
            const size_t trow = (size_t)(t + 1) * KVB * HIDD;
            const short* v0 = Vbase + trow + (size_t)(2 * kp) * HIDD + dq * 16;
            vr0 = *(const bf16x8*)v0;
            vr1 = *(const bf16x8*)(v0 + 8);
            vr2 = *(const bf16x8*)(v0 + HIDD);
            vr3 = *(const bf16x8*)(v0 + HIDD + 8);
#pragma unroll
            for (int i = 0; i < 4; ++i)
                gload_lds16(Kbase + trow + (size_t)kkey[i] * HIDD + kcol[i],
                            &Ksh[c ^ 1][w * 2048 + i * 512]);
        }

        // ---- QK^T on buf c, both branches ----
        f32x4 sc1[4] = {}; f32x4 sc2[4] = {};
        __builtin_amdgcn_s_setprio(1);
#pragma unroll
        for (int sub = 0; sub < 4; ++sub) {
            const short* krow = &Ksh[c][(sub * 16 + lq) * 128];
            bf16x8 k00 = *(const bf16x8*)&krow[(lg * 8) ^ rsw];
            bf16x8 k01 = *(const bf16x8*)&krow[(32 + lg * 8) ^ rsw];
            bf16x8 k10 = *(const bf16x8*)&krow[(64 + lg * 8) ^ rsw];
            bf16x8 k11 = *(const bf16x8*)&krow[(96 + lg * 8) ^ rsw];
            sc1[sub] = MFMA16(k00, qf[0][0], sc1[sub]);
            sc1[sub] = MFMA16(k01, qf[0][1], sc1[sub]);
            sc2[sub] = MFMA16(k10, qf[1][0], sc2[sub]);
            sc2[sub] = MFMA16(k11, qf[1][1], sc2[sub]);
        }
        __builtin_amdgcn_s_setprio(0);
        const int t0 = t * KVB;
        const bool domask = (t0 + KVB - 1 > s0 + w * 16);
        bf16x8 pa1[2], pa2[2];
        softmax_step(sc1, M1, L1, O1, pa1, t0, qg, lg, domask);
        softmax_step(sc2, M2, L2, O2, pa2, t0, qg, lg, domask);

        // ---- VT write for tile t+1 (V-read latency covered by QK+softmax) --
        if (stage) {
#pragma unroll
            for (int j = 0; j < 8; ++j) {
                unsigned ua = (unsigned)(unsigned short)vr0[j] |
                              ((unsigned)(unsigned short)vr2[j] << 16);
                *(unsigned*)&VT[c ^ 1][(dq * 16 + j) * 72 + 2 * kp] = ua;
                unsigned ub = (unsigned)(unsigned short)vr1[j] |
                              ((unsigned)(unsigned short)vr3[j] << 16);
                *(unsigned*)&VT[c ^ 1][(dq * 16 + 8 + j) * 72 + 2 * kp] = ub;
            }
        }

        // ---- PV on buf c ----
        __builtin_amdgcn_s_setprio(1);
#pragma unroll
        for (int d0 = 0; d0 < 8; ++d0) {
            const short* vrow = &VT[c][(d0 * 16 + lq) * 72];
            bf16x4 a0 = *(const bf16x4*)&vrow[lg * 4];
            bf16x4 a1 = *(const bf16x4*)&vrow[16 + lg * 4];
            bf16x4 b0 = *(const bf16x4*)&vrow[32 + lg * 4];
            bf16x4 b1 = *(const bf16x4*)&vrow[48 + lg * 4];
            bf16x8 vb0 = __builtin_shufflevector(a0, a1, 0, 1, 2, 3, 4, 5, 6, 7);
            bf16x8 vb1 = __builtin_shufflevector(b0, b1, 0, 1, 2, 3, 4, 5, 6, 7);
            O1[d0] = MFMA16(pa1[0], vb0, O1[d0]);
            O1[d0] = MFMA16(pa1[1], vb1, O1[d0]);
            O2[d0] = MFMA16(pa2[0], vb0, O2[d0]);
            O2[d0] = MFMA16(pa2[1], vb1, O2[d0]);
        }
        __builtin_amdgcn_s_setprio(0);

        if (stage) waitv0();   // K gload_lds for t+1 complete
        waitl0();              // VT writes visible
        SBAR();
    }

    // ---- epilogue: differential combine + RMSNorm + scales ----
    const float inv1 = 1.f / L1;
    const float inv2 = lam / L2;
    float i1[4], i2[4];
#pragma unroll
    for (int r = 0; r < 4; ++r) {
        i1[r] = __shfl(inv1, lg * 4 + r);
        i2[r] = __shfl(inv2, lg * 4 + r);
    }
    float gn[8];
#pragma unroll
    for (int d = 0; d < 8; ++d) gn[d] = gnw[d * 16 + lq];
    float od[8][4];
    float ss[4] = {0.f, 0.f, 0.f, 0.f};
#pragma unroll
    for (int d = 0; d < 8; ++d)
#pragma unroll
        for (int r = 0; r < 4; ++r) {
            float o = O1[d][r] * i1[r] - O2[d][r] * i2[r];
            od[d][r] = o;
            ss[r] += o * o;
        }
#pragma unroll
    for (int r = 0; r < 4; ++r) {
        ss[r] += __shfl_xor(ss[r], 1);
        ss[r] += __shfl_xor(ss[r], 2);
        ss[r] += __shfl_xor(ss[r], 4);
        ss[r] += __shfl_xor(ss[r], 8);
    }
#pragma unroll
    for (int r = 0; r < 4; ++r) {
        const float scal = rsqrtf(ss[r] * (1.0f / HDD) + EPS_F) * (1.0f - LAMBDA_INIT_F);
        const size_t orow = ((size_t)(b * SDIM + s0 + w * 16 + lg * 4 + r)) * HIDD + h * HDD;
#pragma unroll
        for (int d = 0; d < 8; ++d)
            Hob[orow + d * 16 + lq] = f2bf(od[d][r] * scal * gn[d]);
    }
}

// ----------------------------------------------------------------- launch ---
extern "C" void kernel_launch(void* const* d_in, const int* in_sizes, int n_in,
                              void* d_out, int out_size, void* d_ws, size_t ws_size,
                              hipStream_t stream) {
    const float* q   = (const float*)d_in[0];
    const float* k   = (const float*)d_in[1];
    const float* v   = (const float*)d_in[2];
    const float* Wq  = (const float*)d_in[3];
    const float* Wk  = (const float*)d_in[4];
    const float* Wv  = (const float*)d_in[5];
    const float* Wo  = (const float*)d_in[6];
    const float* lq1 = (const float*)d_in[7];
    const float* lk1 = (const float*)d_in[8];
    const float* lq2 = (const float*)d_in[9];
    const float* lk2 = (const float*)d_in[10];
    const float* gnw = (const float*)d_in[11];
    const float* cosE = (const float*)d_in[12];
    const float* sinE = (const float*)d_in[13];
    float* out = (float*)d_out;

    const size_t TEN = (size_t)BDIM * SDIM * HIDD;  // 8388608
    const int   WN  = HIDD * HIDD;                  // 4194304

    short* wsS = (short*)d_ws;
    short* Qb   = wsS;
    short* Kb   = wsS + TEN;
    short* Vb   = wsS + 2 * TEN;
    short* xqkv = wsS + 3 * TEN;
    short* wb4  = wsS + 6 * TEN;
    float* lamp = (float*)(wsS + 6 * TEN + (size_t)4 * WN);
    short* Hob  = xqkv;

    lambda_kernel<<<1, 64, 0, stream>>>(lq1, lk1, lq2, lk2, lamp);

    dim3 gx((int)(TEN / 8 / 256), 3);
    conv_x<<<gx, 256, 0, stream>>>(q, k, v, xqkv, (int)TEN);
    dim3 gw(WN / 8 / 256, 4);
    conv_w<<<gw, 256, 0, stream>>>(Wq, Wk, Wv, Wo, wb4, WN);

    dim3 gq(HIDD / 128, MTOT / 128, 3);
    qkv_gemm<<<gq, 256, 0, stream>>>(xqkv, xqkv + TEN, xqkv + 2 * TEN, wb4,
                                     Qb, Kb, Vb, cosE, sinE);

    flash_mfma<<<(SDIM / 64) * BDIM * NHH, 256, 0, stream>>>(Qb, Kb, Vb, gnw, lamp, Hob);

    dim3 go(HIDD / 128, MTOT / 128);
    o_gemm<<<go, 256, 0, stream>>>(Hob, wb4 + (size_t)3 * WN, out);
}

// Round 10
// 313.823 us; speedup vs baseline: 1.1665x; 1.0273x over previous
//
#include <hip/hip_runtime.h>
#include <math.h>

#define BDIM 2
#define SDIM 2048
#define HIDD 2048
#define NHH 16
#define HDD 128
#define QKDD 64
#define MTOT (BDIM*SDIM)   // 4096

constexpr float LAMBDA_INIT_F = 0.3555090675909693f;  // 0.8 - 0.6*exp(-0.3)
constexpr float EPS_F = 1e-6f;
constexpr float SCALE2_F = 0.18033688011112042f;      // (1/8) * log2(e)

typedef float f32x4 __attribute__((ext_vector_type(4)));
typedef short bf16x8 __attribute__((ext_vector_type(8)));
typedef short bf16x4 __attribute__((ext_vector_type(4)));

#define MFMA16(a, b, c) __builtin_amdgcn_mfma_f32_16x16x32_bf16((a), (b), (c), 0, 0, 0)

__device__ __forceinline__ short f2bf(float f) {
    unsigned u = __float_as_uint(f);
    u += 0x7FFFu + ((u >> 16) & 1u);   // RNE
    return (short)(u >> 16);
}
__device__ __forceinline__ unsigned pk2(float a, float b) {
    return (unsigned)(unsigned short)f2bf(a) | ((unsigned)(unsigned short)f2bf(b) << 16);
}

__device__ __forceinline__ void gload_lds16(const void* g, void* l) {
    __builtin_amdgcn_global_load_lds(
        (const __attribute__((address_space(1))) void*)g,
        (__attribute__((address_space(3))) void*)l, 16, 0, 0);
}
__device__ __forceinline__ void waitv8() { asm volatile("s_waitcnt vmcnt(8)" ::: "memory"); }
__device__ __forceinline__ void waitv0() { asm volatile("s_waitcnt vmcnt(0)" ::: "memory"); }
__device__ __forceinline__ void waitl0() { asm volatile("s_waitcnt lgkmcnt(0)" ::: "memory"); }
#define SBAR()   __builtin_amdgcn_s_barrier()
#define SCHEDB() __builtin_amdgcn_sched_barrier(0)

// ---------------------------------------------------------------- lambda ----
__global__ void lambda_kernel(const float* __restrict__ lq1, const float* __restrict__ lk1,
                              const float* __restrict__ lq2, const float* __restrict__ lk2,
                              float* __restrict__ lam_out) {
    int l = threadIdx.x;
    float d1 = lq1[l] * lk1[l] + lq1[l + 64] * lk1[l + 64];
    float d2 = lq2[l] * lk2[l] + lq2[l + 64] * lk2[l + 64];
#pragma unroll
    for (int o = 32; o > 0; o >>= 1) {
        d1 += __shfl_down(d1, o);
        d2 += __shfl_down(d2, o);
    }
    if (l == 0) lam_out[0] = expf(d1) - expf(d2) + LAMBDA_INIT_F;
}

// ---------------------------------------------------------------- convert ---
// One launch, 7 slices: y=0..2 -> q,k,v (n=nx); y=3..6 -> Wq,Wk,Wv,Wo (n=nw).
__global__ __launch_bounds__(256) void conv_all(
        const float* __restrict__ q, const float* __restrict__ k,
        const float* __restrict__ v, const float* __restrict__ Wq,
        const float* __restrict__ Wk, const float* __restrict__ Wv,
        const float* __restrict__ Wo, short* __restrict__ xdst,
        short* __restrict__ wdst, int nx, int nw) {
    const int y = blockIdx.y;
    const float* src;
    short* out;
    int n;
    if (y < 3) {
        src = (y == 0) ? q : (y == 1) ? k : v;
        out = xdst + (size_t)y * nx;
        n = nx;
    } else {
        src = (y == 3) ? Wq : (y == 4) ? Wk : (y == 5) ? Wv : Wo;
        out = wdst + (size_t)(y - 3) * nw;
        n = nw;
    }
    int i = (blockIdx.x * 256 + threadIdx.x) * 8;
    if (i >= n) return;
    float4 a = *(const float4*)&src[i];
    float4 b = *(const float4*)&src[i + 4];
    uint4 o;
    o.x = pk2(a.x, a.y); o.y = pk2(a.z, a.w);
    o.z = pk2(b.x, b.y); o.w = pk2(b.z, b.w);
    *(uint4*)&out[i] = o;
}

// ------------------------------------------------------------ bf16 GEMM -----
// C[M,N] = X[M,K](bf16) @ W[N,K]^T(bf16). 128x128 tile, BK=64, 4 waves (2x2).
// Double-buffered LDS + counted vmcnt pipeline (round-7 validated).
#define GK 2048

__device__ __forceinline__ void gemm_mainloop(
        const short* __restrict__ X, const short* __restrict__ W,
        short* As, short* Bs, f32x4 acc[4][4],
        int bm, int bn, int w, int l, int lq, int lg, int wr, int wc) {
    const int scol = (((l & 7) ^ (l >> 3)) << 3);
    const int rsw  = (lq & 7) << 3;
    const short* aS[4]; const short* bS[4];
#pragma unroll
    for (int i = 0; i < 4; ++i) {
        const int c = w * 4 + i;
        aS[i] = X + (size_t)(bm + c * 8 + (l >> 3)) * GK + scol;
        bS[i] = W + (size_t)(bn + c * 8 + (l >> 3)) * GK + scol;
    }
    const int dOff = (w * 4) * 512;

#pragma unroll
    for (int i = 0; i < 4; ++i) {
        gload_lds16(aS[i], As + dOff + i * 512);
        gload_lds16(bS[i], Bs + dOff + i * 512);
    }
#pragma unroll
    for (int i = 0; i < 4; ++i) {
        gload_lds16(aS[i] + 64, As + 8192 + dOff + i * 512);
        gload_lds16(bS[i] + 64, Bs + 8192 + dOff + i * 512);
    }
    waitv8();
    SBAR();

    for (int t = 0; t < 30; ++t) {
        const short* Ab = As + (t & 1) * 8192;
        const short* Bb = Bs + (t & 1) * 8192;
        bf16x8 a[4][2], b[4][2];
#pragma unroll
        for (int m = 0; m < 4; ++m)
#pragma unroll
            for (int kk = 0; kk < 2; ++kk)
                a[m][kk] = *(const bf16x8*)&Ab[(wr * 64 + m * 16 + lq) * 64 + ((kk * 32 + lg * 8) ^ rsw)];
#pragma unroll
        for (int n = 0; n < 4; ++n)
#pragma unroll
            for (int kk = 0; kk < 2; ++kk)
                b[n][kk] = *(const bf16x8*)&Bb[(wc * 64 + n * 16 + lq) * 64 + ((kk * 32 + lg * 8) ^ rsw)];
        waitl0(); SCHEDB();
        SBAR();
        {
            short* Ad = As + (t & 1) * 8192 + dOff;
            short* Bd = Bs + (t & 1) * 8192 + dOff;
#pragma unroll
            for (int i = 0; i < 4; ++i) {
                gload_lds16(aS[i] + (t + 2) * 64, Ad + i * 512);
                gload_lds16(bS[i] + (t + 2) * 64, Bd + i * 512);
            }
        }
        SCHEDB();
#pragma unroll
        for (int kk = 0; kk < 2; ++kk)
#pragma unroll
            for (int m = 0; m < 4; ++m)
#pragma unroll
                for (int n = 0; n < 4; ++n)
                    acc[m][n] = MFMA16(a[m][kk], b[n][kk], acc[m][n]);
        waitv8();
        SBAR();
    }
    {
        bf16x8 a[4][2], b[4][2];
#pragma unroll
        for (int m = 0; m < 4; ++m)
#pragma unroll
            for (int kk = 0; kk < 2; ++kk)
                a[m][kk] = *(const bf16x8*)&As[(wr * 64 + m * 16 + lq) * 64 + ((kk * 32 + lg * 8) ^ rsw)];
#pragma unroll
        for (int n = 0; n < 4; ++n)
#pragma unroll
            for (int kk = 0; kk < 2; ++kk)
                b[n][kk] = *(const bf16x8*)&Bs[(wc * 64 + n * 16 + lq) * 64 + ((kk * 32 + lg * 8) ^ rsw)];
        waitl0(); SCHEDB();
        SBAR();
#pragma unroll
        for (int kk = 0; kk < 2; ++kk)
#pragma unroll
            for (int m = 0; m < 4; ++m)
#pragma unroll
                for (int n = 0; n < 4; ++n)
                    acc[m][n] = MFMA16(a[m][kk], b[n][kk], acc[m][n]);
        waitv0();
        SBAR();
    }
    {
        bf16x8 a[4][2], b[4][2];
#pragma unroll
        for (int m = 0; m < 4; ++m)
#pragma unroll
            for (int kk = 0; kk < 2; ++kk)
                a[m][kk] = *(const bf16x8*)&As[8192 + (wr * 64 + m * 16 + lq) * 64 + ((kk * 32 + lg * 8) ^ rsw)];
#pragma unroll
        for (int n = 0; n < 4; ++n)
#pragma unroll
            for (int kk = 0; kk < 2; ++kk)
                b[n][kk] = *(const bf16x8*)&Bs[8192 + (wc * 64 + n * 16 + lq) * 64 + ((kk * 32 + lg * 8) ^ rsw)];
#pragma unroll
        for (int kk = 0; kk < 2; ++kk)
#pragma unroll
            for (int m = 0; m < 4; ++m)
#pragma unroll
                for (int n = 0; n < 4; ++n)
                    acc[m][n] = MFMA16(a[m][kk], b[n][kk], acc[m][n]);
    }
}

// Batched QKV projection: z=0 -> Q (RoPE), z=1 -> K (RoPE), z=2 -> V (plain).
__global__ __launch_bounds__(256) void qkv_gemm(
        const short* __restrict__ Xq, const short* __restrict__ Xk, const short* __restrict__ Xv,
        const short* __restrict__ Wb, short* __restrict__ Qb, short* __restrict__ Kb,
        short* __restrict__ Vb, const float* __restrict__ cosE, const float* __restrict__ sinE) {
    __shared__ short As[2 * 128 * 64];
    __shared__ short Bs[2 * 128 * 64];
    const int tid = threadIdx.x;
    const int w = tid >> 6, l = tid & 63;
    const int lq = l & 15, lg = l >> 4;
    const int wr = w >> 1, wc = w & 1;
    const int bm = blockIdx.y * 128;
    const int bn = blockIdx.x * 128;
    const int z  = blockIdx.z;

    const short* X = (z == 0) ? Xq : (z == 1) ? Xk : Xv;
    const short* W = Wb + (size_t)z * HIDD * HIDD;
    short* Cb      = (z == 0) ? Qb : (z == 1) ? Kb : Vb;

    f32x4 acc[4][4] = {};
    gemm_mainloop(X, W, As, Bs, acc, bm, bn, w, l, lq, lg, wr, wc);

    const bool dorope = (z < 2);
#pragma unroll
    for (int m = 0; m < 4; ++m)
#pragma unroll
        for (int n = 0; n < 4; ++n) {
            const int row0 = bm + wr * 64 + m * 16 + lg * 4;
            const int col  = bn + wc * 64 + n * 16 + lq;
#pragma unroll
            for (int r = 0; r < 4; ++r) {
                float vv = acc[m][n][r];
                if (dorope) {
                    const int s  = (row0 + r) & (SDIM - 1);
                    const int c6 = col & 63;
                    const float cv = cosE[s * HDD + c6];
                    const float sv = sinE[s * HDD + c6];
                    const float p = __shfl_xor(vv, 1);
                    vv = (col & 1) ? vv * cv + p * sv : vv * cv - p * sv;
                }
                Cb[(size_t)(row0 + r) * HIDD + col] = f2bf(vv);
            }
        }
}

// Output projection: fp32 C.
__global__ __launch_bounds__(256) void o_gemm(const short* __restrict__ Ab,
                                              const short* __restrict__ Bb,
                                              float* __restrict__ C) {
    __shared__ short As[2 * 128 * 64];
    __shared__ short Bs[2 * 128 * 64];
    const int tid = threadIdx.x;
    const int w = tid >> 6, l = tid & 63;
    const int lq = l & 15, lg = l >> 4;
    const int wr = w >> 1, wc = w & 1;
    const int bm = blockIdx.y * 128;
    const int bn = blockIdx.x * 128;

    f32x4 acc[4][4] = {};
    gemm_mainloop(Ab, Bb, As, Bs, acc, bm, bn, w, l, lq, lg, wr, wc);

#pragma unroll
    for (int m = 0; m < 4; ++m)
#pragma unroll
        for (int n = 0; n < 4; ++n) {
            const int row0 = bm + wr * 64 + m * 16 + lg * 4;
            const int col  = bn + wc * 64 + n * 16 + lq;
#pragma unroll
            for (int r = 0; r < 4; ++r)
                C[(size_t)(row0 + r) * HIDD + col] = acc[m][n][r];
        }
}

// ------------------------------------------------- MFMA differential flash --
// Round-7 validated structure (single-buffer staging, cross-block TLP hides
// latency at ~4 blocks/CU) + exp2-domain softmax (scores scaled by log2e/8,
// v_exp_f32 used directly -> one v_mul per exp saved; identical math).
#define KVB 64

__device__ __forceinline__ bf16x8 pack_pa(const float p0[4], const float p1[4]) {
    union { unsigned u[4]; bf16x8 v; } r;
    r.u[0] = pk2(p0[0], p0[1]);
    r.u[1] = pk2(p0[2], p0[3]);
    r.u[2] = pk2(p1[0], p1[1]);
    r.u[3] = pk2(p1[2], p1[3]);
    return r.v;
}

__device__ __forceinline__ void softmax_step(
        f32x4 sc[4], float& M, float& L, f32x4 O[8], bf16x8 pa[2],
        int t0, int qg, int lg, bool domask) {
    // scores -> base-2 domain: s2 = (S / sqrt(64)) * log2(e)
#pragma unroll
    for (int sub = 0; sub < 4; ++sub)
#pragma unroll
        for (int r = 0; r < 4; ++r) {
            float s = sc[sub][r] * SCALE2_F;
            if (domask) {
                int key = t0 + sub * 16 + lg * 4 + r;
                s = (key <= qg) ? s : -1e30f;
            }
            sc[sub][r] = s;
        }
    float mx = -1e30f;
#pragma unroll
    for (int sub = 0; sub < 4; ++sub) {
        float a01 = fmaxf(sc[sub][0], sc[sub][1]);
        float a23 = fmaxf(sc[sub][2], sc[sub][3]);
        mx = fmaxf(mx, fmaxf(a01, a23));
    }
    mx = fmaxf(mx, __shfl_xor(mx, 16));
    mx = fmaxf(mx, __shfl_xor(mx, 32));
    if (__ballot(mx > M + 8.f)) {           // defer-max: P bounded by 2^8
        const float Mn = fmaxf(M, mx);
        const float a = __builtin_amdgcn_exp2f(M - Mn);
        M = Mn;
        L *= a;
        float ar[4];
#pragma unroll
        for (int r = 0; r < 4; ++r) ar[r] = __shfl(a, lg * 4 + r);
#pragma unroll
        for (int d = 0; d < 8; ++d) {
            O[d][0] *= ar[0]; O[d][1] *= ar[1]; O[d][2] *= ar[2]; O[d][3] *= ar[3];
        }
    }
    float p[4][4];
    float ps = 0.f;
#pragma unroll
    for (int sub = 0; sub < 4; ++sub) {
#pragma unroll
        for (int r = 0; r < 4; ++r) p[sub][r] = __builtin_amdgcn_exp2f(sc[sub][r] - M);
        ps += (p[sub][0] + p[sub][1]) + (p[sub][2] + p[sub][3]);
    }
    ps += __shfl_xor(ps, 16);
    ps += __shfl_xor(ps, 32);
    L += ps;
    pa[0] = pack_pa(p[0], p[1]);
    pa[1] = pack_pa(p[2], p[3]);
}

__global__ __launch_bounds__(256, 2) void flash_mfma(
        const short* __restrict__ Qb, const short* __restrict__ Kb,
        const short* __restrict__ Vb, const float* __restrict__ gnw,
        const float* __restrict__ lam_p, short* __restrict__ Hob) {
    __shared__ short Ksh[KVB * 128];   // row-major, 16B-group xor-swizzled
    __shared__ short VT[HDD * 72];     // VT[d][key], row stride 72 shorts

    const int tid = threadIdx.x;
    const int w  = tid >> 6;
    const int l  = tid & 63;
    const int lq = l & 15;
    const int lg = l >> 4;

    const int blk = blockIdx.x;
    const int bh  = blk & 31;
    const int bx  = 31 - (blk >> 5);      // heavy blocks first
    const int b = bh >> 4, h = bh & 15;
    const int s0 = bx * 64;
    const float lam = lam_p[0];

    const int qg = s0 + w * 16 + lq;
    const short* qrow = Qb + ((size_t)(b * SDIM + qg)) * HIDD + h * HDD;
    bf16x8 qf[2][2];
#pragma unroll
    for (int br = 0; br < 2; ++br)
#pragma unroll
        for (int ks = 0; ks < 2; ++ks)
            qf[br][ks] = *(const bf16x8*)(qrow + br * 64 + ks * 32 + lg * 8);

    int kkey[4], kcol[4];
#pragma unroll
    for (int i = 0; i < 4; ++i) {
        kkey[i] = w * 16 + i * 4 + lg;
        kcol[i] = (lq * 8) ^ ((kkey[i] & 7) << 3);
    }
    const int kp = tid & 31, dq = tid >> 5;

    const short* Kbase = Kb + ((size_t)(b * SDIM)) * HIDD + h * HDD;
    const short* Vbase = Vb + ((size_t)(b * SDIM)) * HIDD + h * HDD;

    float M1 = -1e30f, M2 = -1e30f, L1 = 0.f, L2 = 0.f;
    f32x4 O1[8] = {}; f32x4 O2[8] = {};

    const int ntmax = bx + 1;
    const int qmin = s0 + w * 16;
    const int ntw = (qmin >> 6) + 1;

    for (int t = 0; t < ntmax; ++t) {
        const size_t trow = (size_t)t * KVB * HIDD;
        __syncthreads();
#pragma unroll
        for (int i = 0; i < 4; ++i)
            gload_lds16(Kbase + trow + (size_t)kkey[i] * HIDD + kcol[i],
                        &Ksh[w * 2048 + i * 512]);
        {
            const short* v0 = Vbase + trow + (size_t)(2 * kp) * HIDD + dq * 16;
            const short* v1 = v0 + HIDD;
            bf16x8 v00 = *(const bf16x8*)v0;
            bf16x8 v01 = *(const bf16x8*)(v0 + 8);
            bf16x8 v10 = *(const bf16x8*)v1;
            bf16x8 v11 = *(const bf16x8*)(v1 + 8);
#pragma unroll
            for (int j = 0; j < 8; ++j) {
                unsigned ua = (unsigned)(unsigned short)v00[j] |
                              ((unsigned)(unsigned short)v10[j] << 16);
                *(unsigned*)&VT[(dq * 16 + j) * 72 + 2 * kp] = ua;
                unsigned ub = (unsigned)(unsigned short)v01[j] |
                              ((unsigned)(unsigned short)v11[j] << 16);
                *(unsigned*)&VT[(dq * 16 + 8 + j) * 72 + 2 * kp] = ub;
            }
        }
        __syncthreads();
        if (t >= ntw) continue;

        f32x4 sc1[4] = {}; f32x4 sc2[4] = {};
        const int rsw = (lq & 7) << 3;
        __builtin_amdgcn_s_setprio(1);
#pragma unroll
        for (int sub = 0; sub < 4; ++sub) {
            const int rbase = (sub * 16 + lq) * 128;
            bf16x8 k00 = *(const bf16x8*)&Ksh[rbase + ((lg * 8) ^ rsw)];
            bf16x8 k01 = *(const bf16x8*)&Ksh[rbase + ((32 + lg * 8) ^ rsw)];
            bf16x8 k10 = *(const bf16x8*)&Ksh[rbase + ((64 + lg * 8) ^ rsw)];
            bf16x8 k11 = *(const bf16x8*)&Ksh[rbase + ((96 + lg * 8) ^ rsw)];
            sc1[sub] = MFMA16(k00, qf[0][0], sc1[sub]);
            sc1[sub] = MFMA16(k01, qf[0][1], sc1[sub]);
            sc2[sub] = MFMA16(k10, qf[1][0], sc2[sub]);
            sc2[sub] = MFMA16(k11, qf[1][1], sc2[sub]);
        }
        __builtin_amdgcn_s_setprio(0);
        const int t0 = t * KVB;
        const bool domask = (t0 + KVB - 1 > qmin);
        bf16x8 pa1[2], pa2[2];
        softmax_step(sc1, M1, L1, O1, pa1, t0, qg, lg, domask);
        softmax_step(sc2, M2, L2, O2, pa2, t0, qg, lg, domask);

        __builtin_amdgcn_s_setprio(1);
#pragma unroll
        for (int d0 = 0; d0 < 8; ++d0) {
            const short* vrow = &VT[(d0 * 16 + lq) * 72];
            bf16x4 a0 = *(const bf16x4*)&vrow[lg * 4];
            bf16x4 a1 = *(const bf16x4*)&vrow[16 + lg * 4];
            bf16x4 b0 = *(const bf16x4*)&vrow[32 + lg * 4];
            bf16x4 b1 = *(const bf16x4*)&vrow[48 + lg * 4];
            bf16x8 vb0 = __builtin_shufflevector(a0, a1, 0, 1, 2, 3, 4, 5, 6, 7);
            bf16x8 vb1 = __builtin_shufflevector(b0, b1, 0, 1, 2, 3, 4, 5, 6, 7);
            O1[d0] = MFMA16(pa1[0], vb0, O1[d0]);
            O1[d0] = MFMA16(pa1[1], vb1, O1[d0]);
            O2[d0] = MFMA16(pa2[0], vb0, O2[d0]);
            O2[d0] = MFMA16(pa2[1], vb1, O2[d0]);
        }
        __builtin_amdgcn_s_setprio(0);
    }

    const float inv1 = 1.f / L1;
    const float inv2 = lam / L2;
    float i1[4], i2[4];
#pragma unroll
    for (int r = 0; r < 4; ++r) {
        i1[r] = __shfl(inv1, lg * 4 + r);
        i2[r] = __shfl(inv2, lg * 4 + r);
    }
    float gn[8];
#pragma unroll
    for (int d = 0; d < 8; ++d) gn[d] = gnw[d * 16 + lq];
    float od[8][4];
    float ss[4] = {0.f, 0.f, 0.f, 0.f};
#pragma unroll
    for (int d = 0; d < 8; ++d)
#pragma unroll
        for (int r = 0; r < 4; ++r) {
            float o = O1[d][r] * i1[r] - O2[d][r] * i2[r];
            od[d][r] = o;
            ss[r] += o * o;
        }
#pragma unroll
    for (int r = 0; r < 4; ++r) {
        ss[r] += __shfl_xor(ss[r], 1);
        ss[r] += __shfl_xor(ss[r], 2);
        ss[r] += __shfl_xor(ss[r], 4);
        ss[r] += __shfl_xor(ss[r], 8);
    }
#pragma unroll
    for (int r = 0; r < 4; ++r) {
        const float scal = rsqrtf(ss[r] * (1.0f / HDD) + EPS_F) * (1.0f - LAMBDA_INIT_F);
        const size_t orow = ((size_t)(b * SDIM + s0 + w * 16 + lg * 4 + r)) * HIDD + h * HDD;
#pragma unroll
        for (int d = 0; d < 8; ++d)
            Hob[orow + d * 16 + lq] = f2bf(od[d][r] * scal * gn[d]);
    }
}

// ----------------------------------------------------------------- launch ---
extern "C" void kernel_launch(void* const* d_in, const int* in_sizes, int n_in,
                              void* d_out, int out_size, void* d_ws, size_t ws_size,
                              hipStream_t stream) {
    const float* q   = (const float*)d_in[0];
    const float* k   = (const float*)d_in[1];
    const float* v   = (const float*)d_in[2];
    const float* Wq  = (const float*)d_in[3];
    const float* Wk  = (const float*)d_in[4];
    const float* Wv  = (const float*)d_in[5];
    const float* Wo  = (const float*)d_in[6];
    const float* lq1 = (const float*)d_in[7];
    const float* lk1 = (const float*)d_in[8];
    const float* lq2 = (const float*)d_in[9];
    const float* lk2 = (const float*)d_in[10];
    const float* gnw = (const float*)d_in[11];
    const float* cosE = (const float*)d_in[12];
    const float* sinE = (const float*)d_in[13];
    float* out = (float*)d_out;

    const size_t TEN = (size_t)BDIM * SDIM * HIDD;  // 8388608
    const int   WN  = HIDD * HIDD;                  // 4194304

    short* wsS = (short*)d_ws;
    short* Qb   = wsS;
    short* Kb   = wsS + TEN;
    short* Vb   = wsS + 2 * TEN;
    short* xqkv = wsS + 3 * TEN;
    short* wb4  = wsS + 6 * TEN;
    float* lamp = (float*)(wsS + 6 * TEN + (size_t)4 * WN);
    short* Hob  = xqkv;

    lambda_kernel<<<1, 64, 0, stream>>>(lq1, lk1, lq2, lk2, lamp);

    dim3 gc((int)(TEN / 8 / 256), 7);
    conv_all<<<gc, 256, 0, stream>>>(q, k, v, Wq, Wk, Wv, Wo, xqkv, wb4,
                                     (int)TEN, WN);

    dim3 gq(HIDD / 128, MTOT / 128, 3);
    qkv_gemm<<<gq, 256, 0, stream>>>(xqkv, xqkv + TEN, xqkv + 2 * TEN, wb4,
                                     Qb, Kb, Vb, cosE, sinE);

    flash_mfma<<<(SDIM / 64) * BDIM * NHH, 256, 0, stream>>>(Qb, Kb, Vb, gnw, lamp, Hob);

    dim3 go(HIDD / 128, MTOT / 128);
    o_gemm<<<go, 256, 0, stream>>>(Hob, wb4 + (size_t)3 * WN, out);
}

// Round 11
// 302.817 us; speedup vs baseline: 1.2089x; 1.0363x over previous
//
#include <hip/hip_runtime.h>
#include <math.h>

#define BDIM 2
#define SDIM 2048
#define HIDD 2048
#define NHH 16
#define HDD 128
#define QKDD 64
#define MTOT (BDIM*SDIM)   // 4096

constexpr float LAMBDA_INIT_F = 0.3555090675909693f;  // 0.8 - 0.6*exp(-0.3)
constexpr float EPS_F = 1e-6f;
constexpr float SCALE2_F = 0.18033688011112042f;      // (1/8) * log2(e)

typedef float f32x4 __attribute__((ext_vector_type(4)));
typedef short bf16x8 __attribute__((ext_vector_type(8)));
typedef short bf16x4 __attribute__((ext_vector_type(4)));

#define MFMA16(a, b, c) __builtin_amdgcn_mfma_f32_16x16x32_bf16((a), (b), (c), 0, 0, 0)

__device__ __forceinline__ short f2bf(float f) {
    unsigned u = __float_as_uint(f);
    u += 0x7FFFu + ((u >> 16) & 1u);   // RNE
    return (short)(u >> 16);
}
__device__ __forceinline__ unsigned pk2(float a, float b) {
    return (unsigned)(unsigned short)f2bf(a) | ((unsigned)(unsigned short)f2bf(b) << 16);
}
// HW packed f32->bf16 (RNE), lo=src0 hi=src1 — T12 primitive, guide syntax.
__device__ __forceinline__ unsigned cvtpk(float lo, float hi) {
    unsigned r;
    asm("v_cvt_pk_bf16_f32 %0, %1, %2" : "=v"(r) : "v"(lo), "v"(hi));
    return r;
}

__device__ __forceinline__ void gload_lds16(const void* g, void* l) {
    __builtin_amdgcn_global_load_lds(
        (const __attribute__((address_space(1))) void*)g,
        (__attribute__((address_space(3))) void*)l, 16, 0, 0);
}
__device__ __forceinline__ void waitv8() { asm volatile("s_waitcnt vmcnt(8)" ::: "memory"); }
__device__ __forceinline__ void waitv0() { asm volatile("s_waitcnt vmcnt(0)" ::: "memory"); }
__device__ __forceinline__ void waitl0() { asm volatile("s_waitcnt lgkmcnt(0)" ::: "memory"); }
#define SBAR()   __builtin_amdgcn_s_barrier()
#define SCHEDB() __builtin_amdgcn_sched_barrier(0)

// ---------------------------------------------------------------- lambda ----
__global__ void lambda_kernel(const float* __restrict__ lq1, const float* __restrict__ lk1,
                              const float* __restrict__ lq2, const float* __restrict__ lk2,
                              float* __restrict__ lam_out) {
    int l = threadIdx.x;
    float d1 = lq1[l] * lk1[l] + lq1[l + 64] * lk1[l + 64];
    float d2 = lq2[l] * lk2[l] + lq2[l + 64] * lk2[l + 64];
#pragma unroll
    for (int o = 32; o > 0; o >>= 1) {
        d1 += __shfl_down(d1, o);
        d2 += __shfl_down(d2, o);
    }
    if (l == 0) lam_out[0] = expf(d1) - expf(d2) + LAMBDA_INIT_F;
}

// ---------------------------------------------------------------- convert ---
// Exact-span 1D grid: regions [q|k|v] (2^23 each) then [Wq|Wk|Wv|Wo] (2^22).
// Total 41943040 elements / 2048 per block = 20480 blocks, zero dead blocks.
__global__ __launch_bounds__(256) void conv_all(
        const float* __restrict__ q, const float* __restrict__ k,
        const float* __restrict__ v, const float* __restrict__ Wq,
        const float* __restrict__ Wk, const float* __restrict__ Wv,
        const float* __restrict__ Wo, short* __restrict__ xdst,
        short* __restrict__ wdst) {
    const size_t TEN_C = (size_t)1 << 23;
    const size_t WN_C  = (size_t)1 << 22;
    size_t i = ((size_t)blockIdx.x * 256 + threadIdx.x) * 8;
    const float* src;
    short* dst;
    size_t off;
    if (i < 3 * TEN_C) {
        int y = (int)(i >> 23);
        off = i & (TEN_C - 1);
        src = (y == 0) ? q : (y == 1) ? k : v;
        dst = xdst + ((size_t)y << 23);
    } else {
        size_t j = i - 3 * TEN_C;
        int y = (int)(j >> 22);
        off = j & (WN_C - 1);
        src = (y == 0) ? Wq : (y == 1) ? Wk : (y == 2) ? Wv : Wo;
        dst = wdst + ((size_t)y << 22);
    }
    float4 a = *(const float4*)&src[off];
    float4 b = *(const float4*)&src[off + 4];
    uint4 o;
    o.x = pk2(a.x, a.y); o.y = pk2(a.z, a.w);
    o.z = pk2(b.x, b.y); o.w = pk2(b.z, b.w);
    *(uint4*)&dst[off] = o;
}

// ------------------------------------------------------------ bf16 GEMM -----
// C[M,N] = X[M,K](bf16) @ W[N,K]^T(bf16). 128x128 tile, BK=64, 4 waves (2x2).
// Double-buffered LDS + counted vmcnt pipeline (round-7 validated).
#define GK 2048

__device__ __forceinline__ void gemm_mainloop(
        const short* __restrict__ X, const short* __restrict__ W,
        short* As, short* Bs, f32x4 acc[4][4],
        int bm, int bn, int w, int l, int lq, int lg, int wr, int wc) {
    const int scol = (((l & 7) ^ (l >> 3)) << 3);
    const int rsw  = (lq & 7) << 3;
    const short* aS[4]; const short* bS[4];
#pragma unroll
    for (int i = 0; i < 4; ++i) {
        const int c = w * 4 + i;
        aS[i] = X + (size_t)(bm + c * 8 + (l >> 3)) * GK + scol;
        bS[i] = W + (size_t)(bn + c * 8 + (l >> 3)) * GK + scol;
    }
    const int dOff = (w * 4) * 512;

#pragma unroll
    for (int i = 0; i < 4; ++i) {
        gload_lds16(aS[i], As + dOff + i * 512);
        gload_lds16(bS[i], Bs + dOff + i * 512);
    }
#pragma unroll
    for (int i = 0; i < 4; ++i) {
        gload_lds16(aS[i] + 64, As + 8192 + dOff + i * 512);
        gload_lds16(bS[i] + 64, Bs + 8192 + dOff + i * 512);
    }
    waitv8();
    SBAR();

    for (int t = 0; t < 30; ++t) {
        const short* Ab = As + (t & 1) * 8192;
        const short* Bb = Bs + (t & 1) * 8192;
        bf16x8 a[4][2], b[4][2];
#pragma unroll
        for (int m = 0; m < 4; ++m)
#pragma unroll
            for (int kk = 0; kk < 2; ++kk)
                a[m][kk] = *(const bf16x8*)&Ab[(wr * 64 + m * 16 + lq) * 64 + ((kk * 32 + lg * 8) ^ rsw)];
#pragma unroll
        for (int n = 0; n < 4; ++n)
#pragma unroll
            for (int kk = 0; kk < 2; ++kk)
                b[n][kk] = *(const bf16x8*)&Bb[(wc * 64 + n * 16 + lq) * 64 + ((kk * 32 + lg * 8) ^ rsw)];
        waitl0(); SCHEDB();
        SBAR();
        {
            short* Ad = As + (t & 1) * 8192 + dOff;
            short* Bd = Bs + (t & 1) * 8192 + dOff;
#pragma unroll
            for (int i = 0; i < 4; ++i) {
                gload_lds16(aS[i] + (t + 2) * 64, Ad + i * 512);
                gload_lds16(bS[i] + (t + 2) * 64, Bd + i * 512);
            }
        }
        SCHEDB();
#pragma unroll
        for (int kk = 0; kk < 2; ++kk)
#pragma unroll
            for (int m = 0; m < 4; ++m)
#pragma unroll
                for (int n = 0; n < 4; ++n)
                    acc[m][n] = MFMA16(a[m][kk], b[n][kk], acc[m][n]);
        waitv8();
        SBAR();
    }
    {
        bf16x8 a[4][2], b[4][2];
#pragma unroll
        for (int m = 0; m < 4; ++m)
#pragma unroll
            for (int kk = 0; kk < 2; ++kk)
                a[m][kk] = *(const bf16x8*)&As[(wr * 64 + m * 16 + lq) * 64 + ((kk * 32 + lg * 8) ^ rsw)];
#pragma unroll
        for (int n = 0; n < 4; ++n)
#pragma unroll
            for (int kk = 0; kk < 2; ++kk)
                b[n][kk] = *(const bf16x8*)&Bs[(wc * 64 + n * 16 + lq) * 64 + ((kk * 32 + lg * 8) ^ rsw)];
        waitl0(); SCHEDB();
        SBAR();
#pragma unroll
        for (int kk = 0; kk < 2; ++kk)
#pragma unroll
            for (int m = 0; m < 4; ++m)
#pragma unroll
                for (int n = 0; n < 4; ++n)
                    acc[m][n] = MFMA16(a[m][kk], b[n][kk], acc[m][n]);
        waitv0();
        SBAR();
    }
    {
        bf16x8 a[4][2], b[4][2];
#pragma unroll
        for (int m = 0; m < 4; ++m)
#pragma unroll
            for (int kk = 0; kk < 2; ++kk)
                a[m][kk] = *(const bf16x8*)&As[8192 + (wr * 64 + m * 16 + lq) * 64 + ((kk * 32 + lg * 8) ^ rsw)];
#pragma unroll
        for (int n = 0; n < 4; ++n)
#pragma unroll
            for (int kk = 0; kk < 2; ++kk)
                b[n][kk] = *(const bf16x8*)&Bs[8192 + (wc * 64 + n * 16 + lq) * 64 + ((kk * 32 + lg * 8) ^ rsw)];
#pragma unroll
        for (int kk = 0; kk < 2; ++kk)
#pragma unroll
            for (int m = 0; m < 4; ++m)
#pragma unroll
                for (int n = 0; n < 4; ++n)
                    acc[m][n] = MFMA16(a[m][kk], b[n][kk], acc[m][n]);
    }
}

// Batched QKV projection: z=0 -> Q (RoPE), z=1 -> K (RoPE), z=2 -> V (plain).
__global__ __launch_bounds__(256) void qkv_gemm(
        const short* __restrict__ Xq, const short* __restrict__ Xk, const short* __restrict__ Xv,
        const short* __restrict__ Wb, short* __restrict__ Qb, short* __restrict__ Kb,
        short* __restrict__ Vb, const float* __restrict__ cosE, const float* __restrict__ sinE) {
    __shared__ short As[2 * 128 * 64];
    __shared__ short Bs[2 * 128 * 64];
    const int tid = threadIdx.x;
    const int w = tid >> 6, l = tid & 63;
    const int lq = l & 15, lg = l >> 4;
    const int wr = w >> 1, wc = w & 1;
    const int bm = blockIdx.y * 128;
    const int bn = blockIdx.x * 128;
    const int z  = blockIdx.z;

    const short* X = (z == 0) ? Xq : (z == 1) ? Xk : Xv;
    const short* W = Wb + (size_t)z * HIDD * HIDD;
    short* Cb      = (z == 0) ? Qb : (z == 1) ? Kb : Vb;

    f32x4 acc[4][4] = {};
    gemm_mainloop(X, W, As, Bs, acc, bm, bn, w, l, lq, lg, wr, wc);

    const bool dorope = (z < 2);
#pragma unroll
    for (int m = 0; m < 4; ++m)
#pragma unroll
        for (int n = 0; n < 4; ++n) {
            const int row0 = bm + wr * 64 + m * 16 + lg * 4;
            const int col  = bn + wc * 64 + n * 16 + lq;
#pragma unroll
            for (int r = 0; r < 4; ++r) {
                float vv = acc[m][n][r];
                if (dorope) {
                    const int s  = (row0 + r) & (SDIM - 1);
                    const int c6 = col & 63;
                    const float cv = cosE[s * HDD + c6];
                    const float sv = sinE[s * HDD + c6];
                    const float p = __shfl_xor(vv, 1);
                    vv = (col & 1) ? vv * cv + p * sv : vv * cv - p * sv;
                }
                Cb[(size_t)(row0 + r) * HIDD + col] = f2bf(vv);
            }
        }
}

// Output projection: fp32 C.
__global__ __launch_bounds__(256) void o_gemm(const short* __restrict__ Ab,
                                              const short* __restrict__ Bb,
                                              float* __restrict__ C) {
    __shared__ short As[2 * 128 * 64];
    __shared__ short Bs[2 * 128 * 64];
    const int tid = threadIdx.x;
    const int w = tid >> 6, l = tid & 63;
    const int lq = l & 15, lg = l >> 4;
    const int wr = w >> 1, wc = w & 1;
    const int bm = blockIdx.y * 128;
    const int bn = blockIdx.x * 128;

    f32x4 acc[4][4] = {};
    gemm_mainloop(Ab, Bb, As, Bs, acc, bm, bn, w, l, lq, lg, wr, wc);

#pragma unroll
    for (int m = 0; m < 4; ++m)
#pragma unroll
        for (int n = 0; n < 4; ++n) {
            const int row0 = bm + wr * 64 + m * 16 + lg * 4;
            const int col  = bn + wc * 64 + n * 16 + lq;
#pragma unroll
            for (int r = 0; r < 4; ++r)
                C[(size_t)(row0 + r) * HIDD + col] = acc[m][n][r];
        }
}

// ------------------------------------------------- MFMA differential flash --
// Round-7 validated structure + CU load-balance bx permutation + cvt_pk P-pack.
// Balance: assuming sequential block->CU assignment (c, c+256, c+512, c+768),
// rows r=g>>3 map bx as {31-gc, gc, 23-gc, 8+gc} -> every CU sums to 66 tiles.
#define KVB 64

__device__ __forceinline__ bf16x8 pack_pa(const float p0[4], const float p1[4]) {
    union { unsigned u[4]; bf16x8 v; } r;
    r.u[0] = cvtpk(p0[0], p0[1]);
    r.u[1] = cvtpk(p0[2], p0[3]);
    r.u[2] = cvtpk(p1[0], p1[1]);
    r.u[3] = cvtpk(p1[2], p1[3]);
    return r.v;
}

__device__ __forceinline__ void softmax_step(
        f32x4 sc[4], float& M, float& L, f32x4 O[8], bf16x8 pa[2],
        int t0, int qg, int lg, bool domask) {
    // scores -> base-2 domain: s2 = (S / sqrt(64)) * log2(e)
#pragma unroll
    for (int sub = 0; sub < 4; ++sub)
#pragma unroll
        for (int r = 0; r < 4; ++r) {
            float s = sc[sub][r] * SCALE2_F;
            if (domask) {
                int key = t0 + sub * 16 + lg * 4 + r;
                s = (key <= qg) ? s : -1e30f;
            }
            sc[sub][r] = s;
        }
    float mx = -1e30f;
#pragma unroll
    for (int sub = 0; sub < 4; ++sub) {
        float a01 = fmaxf(sc[sub][0], sc[sub][1]);
        float a23 = fmaxf(sc[sub][2], sc[sub][3]);
        mx = fmaxf(mx, fmaxf(a01, a23));
    }
    mx = fmaxf(mx, __shfl_xor(mx, 16));
    mx = fmaxf(mx, __shfl_xor(mx, 32));
    if (__ballot(mx > M + 8.f)) {           // defer-max: P bounded by 2^8
        const float Mn = fmaxf(M, mx);
        const float a = __builtin_amdgcn_exp2f(M - Mn);
        M = Mn;
        L *= a;
        float ar[4];
#pragma unroll
        for (int r = 0; r < 4; ++r) ar[r] = __shfl(a, lg * 4 + r);
#pragma unroll
        for (int d = 0; d < 8; ++d) {
            O[d][0] *= ar[0]; O[d][1] *= ar[1]; O[d][2] *= ar[2]; O[d][3] *= ar[3];
        }
    }
    float p[4][4];
    float ps = 0.f;
#pragma unroll
    for (int sub = 0; sub < 4; ++sub) {
#pragma unroll
        for (int r = 0; r < 4; ++r) p[sub][r] = __builtin_amdgcn_exp2f(sc[sub][r] - M);
        ps += (p[sub][0] + p[sub][1]) + (p[sub][2] + p[sub][3]);
    }
    ps += __shfl_xor(ps, 16);
    ps += __shfl_xor(ps, 32);
    L += ps;
    pa[0] = pack_pa(p[0], p[1]);
    pa[1] = pack_pa(p[2], p[3]);
}

__global__ __launch_bounds__(256, 2) void flash_mfma(
        const short* __restrict__ Qb, const short* __restrict__ Kb,
        const short* __restrict__ Vb, const float* __restrict__ gnw,
        const float* __restrict__ lam_p, short* __restrict__ Hob) {
    __shared__ short Ksh[KVB * 128];   // row-major, 16B-group xor-swizzled
    __shared__ short VT[HDD * 72];     // VT[d][key], row stride 72 shorts

    const int tid = threadIdx.x;
    const int w  = tid >> 6;
    const int l  = tid & 63;
    const int lq = l & 15;
    const int lg = l >> 4;

    const int blk = blockIdx.x;
    const int bh  = blk & 31;
    const int g   = blk >> 5;
    const int r4  = g >> 3, gc = g & 7;
    const int bx  = (r4 == 0) ? 31 - gc : (r4 == 1) ? gc
                  : (r4 == 2) ? 23 - gc : 8 + gc;    // per-CU balanced
    const int b = bh >> 4, h = bh & 15;
    const int s0 = bx * 64;
    const float lam = lam_p[0];

    const int qg = s0 + w * 16 + lq;
    const short* qrow = Qb + ((size_t)(b * SDIM + qg)) * HIDD + h * HDD;
    bf16x8 qf[2][2];
#pragma unroll
    for (int br = 0; br < 2; ++br)
#pragma unroll
        for (int ks = 0; ks < 2; ++ks)
            qf[br][ks] = *(const bf16x8*)(qrow + br * 64 + ks * 32 + lg * 8);

    int kkey[4], kcol[4];
#pragma unroll
    for (int i = 0; i < 4; ++i) {
        kkey[i] = w * 16 + i * 4 + lg;
        kcol[i] = (lq * 8) ^ ((kkey[i] & 7) << 3);
    }
    const int kp = tid & 31, dq = tid >> 5;

    const short* Kbase = Kb + ((size_t)(b * SDIM)) * HIDD + h * HDD;
    const short* Vbase = Vb + ((size_t)(b * SDIM)) * HIDD + h * HDD;

    float M1 = -1e30f, M2 = -1e30f, L1 = 0.f, L2 = 0.f;
    f32x4 O1[8] = {}; f32x4 O2[8] = {};

    const int ntmax = bx + 1;
    const int qmin = s0 + w * 16;

    for (int t = 0; t < ntmax; ++t) {
        const size_t trow = (size_t)t * KVB * HIDD;
        __syncthreads();
#pragma unroll
        for (int i = 0; i < 4; ++i)
            gload_lds16(Kbase + trow + (size_t)kkey[i] * HIDD + kcol[i],
                        &Ksh[w * 2048 + i * 512]);
        {
            const short* v0 = Vbase + trow + (size_t)(2 * kp) * HIDD + dq * 16;
            const short* v1 = v0 + HIDD;
            bf16x8 v00 = *(const bf16x8*)v0;
            bf16x8 v01 = *(const bf16x8*)(v0 + 8);
            bf16x8 v10 = *(const bf16x8*)v1;
            bf16x8 v11 = *(const bf16x8*)(v1 + 8);
#pragma unroll
            for (int j = 0; j < 8; ++j) {
                unsigned ua = (unsigned)(unsigned short)v00[j] |
                              ((unsigned)(unsigned short)v10[j] << 16);
                *(unsigned*)&VT[(dq * 16 + j) * 72 + 2 * kp] = ua;
                unsigned ub = (unsigned)(unsigned short)v01[j] |
                              ((unsigned)(unsigned short)v11[j] << 16);
                *(unsigned*)&VT[(dq * 16 + 8 + j) * 72 + 2 * kp] = ub;
            }
        }
        __syncthreads();

        f32x4 sc1[4] = {}; f32x4 sc2[4] = {};
        const int rsw = (lq & 7) << 3;
        __builtin_amdgcn_s_setprio(1);
#pragma unroll
        for (int sub = 0; sub < 4; ++sub) {
            const int rbase = (sub * 16 + lq) * 128;
            bf16x8 k00 = *(const bf16x8*)&Ksh[rbase + ((lg * 8) ^ rsw)];
            bf16x8 k01 = *(const bf16x8*)&Ksh[rbase + ((32 + lg * 8) ^ rsw)];
            bf16x8 k10 = *(const bf16x8*)&Ksh[rbase + ((64 + lg * 8) ^ rsw)];
            bf16x8 k11 = *(const bf16x8*)&Ksh[rbase + ((96 + lg * 8) ^ rsw)];
            sc1[sub] = MFMA16(k00, qf[0][0], sc1[sub]);
            sc1[sub] = MFMA16(k01, qf[0][1], sc1[sub]);
            sc2[sub] = MFMA16(k10, qf[1][0], sc2[sub]);
            sc2[sub] = MFMA16(k11, qf[1][1], sc2[sub]);
        }
        __builtin_amdgcn_s_setprio(0);
        const int t0 = t * KVB;
        const bool domask = (t0 + KVB - 1 > qmin);
        bf16x8 pa1[2], pa2[2];
        softmax_step(sc1, M1, L1, O1, pa1, t0, qg, lg, domask);
        softmax_step(sc2, M2, L2, O2, pa2, t0, qg, lg, domask);

        __builtin_amdgcn_s_setprio(1);
#pragma unroll
        for (int d0 = 0; d0 < 8; ++d0) {
            const short* vrow = &VT[(d0 * 16 + lq) * 72];
            bf16x4 a0 = *(const bf16x4*)&vrow[lg * 4];
            bf16x4 a1 = *(const bf16x4*)&vrow[16 + lg * 4];
            bf16x4 b0 = *(const bf16x4*)&vrow[32 + lg * 4];
            bf16x4 b1 = *(const bf16x4*)&vrow[48 + lg * 4];
            bf16x8 vb0 = __builtin_shufflevector(a0, a1, 0, 1, 2, 3, 4, 5, 6, 7);
            bf16x8 vb1 = __builtin_shufflevector(b0, b1, 0, 1, 2, 3, 4, 5, 6, 7);
            O1[d0] = MFMA16(pa1[0], vb0, O1[d0]);
            O1[d0] = MFMA16(pa1[1], vb1, O1[d0]);
            O2[d0] = MFMA16(pa2[0], vb0, O2[d0]);
            O2[d0] = MFMA16(pa2[1], vb1, O2[d0]);
        }
        __builtin_amdgcn_s_setprio(0);
    }

    const float inv1 = 1.f / L1;
    const float inv2 = lam / L2;
    float i1[4], i2[4];
#pragma unroll
    for (int r = 0; r < 4; ++r) {
        i1[r] = __shfl(inv1, lg * 4 + r);
        i2[r] = __shfl(inv2, lg * 4 + r);
    }
    float gn[8];
#pragma unroll
    for (int d = 0; d < 8; ++d) gn[d] = gnw[d * 16 + lq];
    float od[8][4];
    float ss[4] = {0.f, 0.f, 0.f, 0.f};
#pragma unroll
    for (int d = 0; d < 8; ++d)
#pragma unroll
        for (int r = 0; r < 4; ++r) {
            float o = O1[d][r] * i1[r] - O2[d][r] * i2[r];
            od[d][r] = o;
            ss[r] += o * o;
        }
#pragma unroll
    for (int r = 0; r < 4; ++r) {
        ss[r] += __shfl_xor(ss[r], 1);
        ss[r] += __shfl_xor(ss[r], 2);
        ss[r] += __shfl_xor(ss[r], 4);
        ss[r] += __shfl_xor(ss[r], 8);
    }
#pragma unroll
    for (int r = 0; r < 4; ++r) {
        const float scal = rsqrtf(ss[r] * (1.0f / HDD) + EPS_F) * (1.0f - LAMBDA_INIT_F);
        const size_t orow = ((size_t)(b * SDIM + s0 + w * 16 + lg * 4 + r)) * HIDD + h * HDD;
#pragma unroll
        for (int d = 0; d < 8; ++d)
            Hob[orow + d * 16 + lq] = f2bf(od[d][r] * scal * gn[d]);
    }
}

// ----------------------------------------------------------------- launch ---
extern "C" void kernel_launch(void* const* d_in, const int* in_sizes, int n_in,
                              void* d_out, int out_size, void* d_ws, size_t ws_size,
                              hipStream_t stream) {
    const float* q   = (const float*)d_in[0];
    const float* k   = (const float*)d_in[1];
    const float* v   = (const float*)d_in[2];
    const float* Wq  = (const float*)d_in[3];
    const float* Wk  = (const float*)d_in[4];
    const float* Wv  = (const float*)d_in[5];
    const float* Wo  = (const float*)d_in[6];
    const float* lq1 = (const float*)d_in[7];
    const float* lk1 = (const float*)d_in[8];
    const float* lq2 = (const float*)d_in[9];
    const float* lk2 = (const float*)d_in[10];
    const float* gnw = (const float*)d_in[11];
    const float* cosE = (const float*)d_in[12];
    const float* sinE = (const float*)d_in[13];
    float* out = (float*)d_out;

    const size_t TEN = (size_t)BDIM * SDIM * HIDD;  // 8388608 = 2^23
    const int   WN  = HIDD * HIDD;                  // 4194304 = 2^22

    short* wsS = (short*)d_ws;
    short* Qb   = wsS;
    short* Kb   = wsS + TEN;
    short* Vb   = wsS + 2 * TEN;
    short* xqkv = wsS + 3 * TEN;
    short* wb4  = wsS + 6 * TEN;
    float* lamp = (float*)(wsS + 6 * TEN + (size_t)4 * WN);
    short* Hob  = xqkv;

    lambda_kernel<<<1, 64, 0, stream>>>(lq1, lk1, lq2, lk2, lamp);

    conv_all<<<20480, 256, 0, stream>>>(q, k, v, Wq, Wk, Wv, Wo, xqkv, wb4);

    dim3 gq(HIDD / 128, MTOT / 128, 3);
    qkv_gemm<<<gq, 256, 0, stream>>>(xqkv, xqkv + TEN, xqkv + 2 * TEN, wb4,
                                     Qb, Kb, Vb, cosE, sinE);

    flash_mfma<<<(SDIM / 64) * BDIM * NHH, 256, 0, stream>>>(Qb, Kb, Vb, gnw, lamp, Hob);

    dim3 go(HIDD / 128, MTOT / 128);
    o_gemm<<<go, 256, 0, stream>>>(Hob, wb4 + (size_t)3 * WN, out);
}